// Round 8
// baseline (262.492 us; speedup 1.0000x reference)
//
#include <hip/hip_runtime.h>

typedef unsigned short u16;
typedef unsigned int   u32;
typedef __attribute__((ext_vector_type(8))) short bf16x8;
typedef __attribute__((ext_vector_type(4))) float f32x4;

// ---------- bf16 helpers (manual, RNE) ----------
__device__ __forceinline__ u16 f2bf(float f) {
    u32 u = __float_as_uint(f);
    u += 0x7fffu + ((u >> 16) & 1u);
    return (u16)(u >> 16);
}
__device__ __forceinline__ float bf2f(u16 s) {
    return __uint_as_float(((u32)s) << 16);
}
__device__ __forceinline__ u32 pack2bf(float f0, float f1) {
    return (u32)f2bf(f0) | ((u32)f2bf(f1) << 16);
}

__device__ __forceinline__ void gload_lds16(const void* g, void* l) {
    __builtin_amdgcn_global_load_lds(
        (const __attribute__((address_space(1))) u32*)g,
        (__attribute__((address_space(3))) u32*)l, 16, 0, 0);
}

// =======================================================================
// fp32 -> bf16 converters
// =======================================================================
__global__ __launch_bounds__(256)
void conv_bf16(const float* __restrict__ src, u16* __restrict__ dst, int n8)
{
    const int i = blockIdx.x * 256 + threadIdx.x;   // 8 elements per thread
    if (i < n8) {
        const float4 a = ((const float4*)src)[2*i];
        const float4 b = ((const float4*)src)[2*i + 1];
        ((uint4*)dst)[i] = make_uint4(pack2bf(a.x,a.y), pack2bf(a.z,a.w),
                                      pack2bf(b.x,b.y), pack2bf(b.z,b.w));
    }
}

// w_qkv [2304][768]: keep q rows 0..767 and v rows 1536..2303 -> wqv [1536][768]
__global__ __launch_bounds__(256)
void conv_wqv(const float* __restrict__ w, u16* __restrict__ dst)
{
    const int i = blockIdx.x * 256 + threadIdx.x;   // chunk of 8, 96 chunks/row
    const int row = i / 96;
    const int cc  = (i - row * 96) * 8;
    const int srow = row + (row >= 768 ? 768 : 0);
    const float4 a = *(const float4*)&w[(size_t)srow*768 + cc];
    const float4 b = *(const float4*)&w[(size_t)srow*768 + cc + 4];
    *(uint4*)&dst[(size_t)row*768 + cc] =
        make_uint4(pack2bf(a.x,a.y), pack2bf(a.z,a.w), pack2bf(b.x,b.y), pack2bf(b.z,b.w));
}

// =======================================================================
// Shared MFMA GEMM core: C[128x128] tile, K=768, bf16 A[.,768] x B[.,768]^T.
// BK=64, 4 waves (2x2), 16x16x32 MFMA, global_load_lds + XOR-swizzled LDS.
// =======================================================================
__device__ __forceinline__ void mfma_gemm_core(
    const char* __restrict__ Arow0,   // &A[m0][0] as bytes (row stride 1536)
    const char* __restrict__ Brow0,   // &B[n0][0] as bytes
    u16* As, u16* Bs, const int tid, f32x4 acc[4][4])
{
    const int l  = tid & 63, w = tid >> 6;
    const int wr = w >> 1,  wc = w & 1;
    char* Asb = (char*)As;
    char* Bsb = (char*)Bs;
    const int co = 16 * ((l & 7) ^ (l >> 3));       // swizzled global byte col
    const size_t rstep = (size_t)(l >> 3) * 1536;
    const int rsw = (l & 7) << 4;                   // read-side XOR

    for (int k0 = 0; k0 < 1536; k0 += 128) {        // 12 K-steps of 64 bf16
        #pragma unroll
        for (int i = 0; i < 4; ++i) {
            const int rb = i*32 + w*8;
            gload_lds16(Arow0 + (size_t)rb*1536 + rstep + k0 + co, Asb + i*4096 + w*1024);
            gload_lds16(Brow0 + (size_t)rb*1536 + rstep + k0 + co, Bsb + i*4096 + w*1024);
        }
        __syncthreads();
        bf16x8 af[2][4], bfr[2][4];
        #pragma unroll
        for (int kk = 0; kk < 2; ++kk) {
            const int coff = (kk*64 + ((l >> 4) << 4)) ^ rsw;
            #pragma unroll
            for (int mi = 0; mi < 4; ++mi) {
                const int rowA = wr*64 + mi*16 + (l & 15);
                af[kk][mi]  = *(const bf16x8*)(Asb + rowA*128 + coff);
                const int rowB = wc*64 + mi*16 + (l & 15);
                bfr[kk][mi] = *(const bf16x8*)(Bsb + rowB*128 + coff);
            }
        }
        #pragma unroll
        for (int mi = 0; mi < 4; ++mi)
            #pragma unroll
            for (int nj = 0; nj < 4; ++nj) {
                acc[mi][nj] = __builtin_amdgcn_mfma_f32_16x16x32_bf16(
                                  af[0][mi], bfr[0][nj], acc[mi][nj], 0, 0, 0);
                acc[mi][nj] = __builtin_amdgcn_mfma_f32_16x16x32_bf16(
                                  af[1][mi], bfr[1][nj], acc[mi][nj], 0, 0, 0);
            }
        __syncthreads();
    }
}

// =======================================================================
// K0: q/v projection + FUSED q-normalize. xbf [16384][768], wqv [1536][768].
// bj<6 -> q cols: each wave's 64 cols = one head (h = 2bj+wc); row-norm via
// 16-lane shfl_xor reduce over nj-frags; writes qn bf16 [bh][n][64] direct.
// bj>=6 -> v cols, written TRANSPOSED as vbfT [bh][d][m] bf16.
// =======================================================================
__global__ __launch_bounds__(256)
void gemm_qkv_mfma(const u16* __restrict__ xbf, const u16* __restrict__ wqv,
                   u16* __restrict__ qnbf, u16* __restrict__ vbfT)
{
    __shared__ u16 As[128*64];
    __shared__ u16 Bs[128*64];
    const int m0 = blockIdx.x * 128;
    const int bj = blockIdx.y;
    const int tid = threadIdx.x;
    f32x4 acc[4][4];
    #pragma unroll
    for (int i = 0; i < 4; ++i)
        #pragma unroll
        for (int j = 0; j < 4; ++j) acc[i][j] = (f32x4){0.f,0.f,0.f,0.f};

    mfma_gemm_core((const char*)xbf + (size_t)m0*1536,
                   (const char*)wqv + (size_t)bj*128*1536,
                   As, Bs, tid, acc);

    const int l = tid & 63, w = tid >> 6;
    const int wr = w >> 1, wc = w & 1;
    const int rbase = m0 + wr*64 + ((l >> 4) << 2);
    if (bj < 6) {
        const int h = 2*bj + wc;                   // wave's 64 cols = head h
        #pragma unroll
        for (int mi = 0; mi < 4; ++mi)
            #pragma unroll
            for (int rr = 0; rr < 4; ++rr) {
                float s =      acc[mi][0][rr]*acc[mi][0][rr];
                s = fmaf(acc[mi][1][rr], acc[mi][1][rr], s);
                s = fmaf(acc[mi][2][rr], acc[mi][2][rr], s);
                s = fmaf(acc[mi][3][rr], acc[mi][3][rr], s);
                #pragma unroll
                for (int off = 1; off < 16; off <<= 1) s += __shfl_xor(s, off);
                const float inv = 1.0f / (sqrtf(s) + 1e-8f);
                const int m = rbase + mi*16 + rr;
                const int b_ = m >> 8, n_ = m & 255;
                u16* row = qnbf + ((((size_t)b_*12 + h) << 8) + n_)*64;
                #pragma unroll
                for (int nj = 0; nj < 4; ++nj)
                    row[nj*16 + (l & 15)] = f2bf(acc[mi][nj][rr] * inv);
            }
    } else {
        const int colb = (bj - 6)*128 + wc*64;
        #pragma unroll
        for (int mi = 0; mi < 4; ++mi)
            #pragma unroll
            for (int nj = 0; nj < 4; ++nj) {
                const int col = colb + nj*16 + (l & 15);
                const int h = col >> 6, d = col & 63;
                const int m = rbase + mi*16;        // rows m..m+3 (consecutive)
                const int b_ = m >> 8, n_ = m & 255;
                uint2 o = make_uint2(pack2bf(acc[mi][nj][0], acc[mi][nj][1]),
                                     pack2bf(acc[mi][nj][2], acc[mi][nj][3]));
                *(uint2*)&vbfT[(((size_t)b_*12 + h)*64 + d)*256 + n_] = o;
            }
    }
}

// =======================================================================
// K5: out = ctx @ w_proj^T + b_proj. ctxb [16384][768] bf16, wpb [768][768] bf16.
// =======================================================================
__global__ __launch_bounds__(256)
void gemm_proj_mfma(const u16* __restrict__ ctxb, const u16* __restrict__ wpb,
                    const float* __restrict__ bias, float* __restrict__ out)
{
    __shared__ u16 As[128*64];
    __shared__ u16 Bs[128*64];
    const int m0 = blockIdx.x * 128;
    const int n0 = blockIdx.y * 128;
    const int tid = threadIdx.x;
    f32x4 acc[4][4];
    #pragma unroll
    for (int i = 0; i < 4; ++i)
        #pragma unroll
        for (int j = 0; j < 4; ++j) acc[i][j] = (f32x4){0.f,0.f,0.f,0.f};

    mfma_gemm_core((const char*)ctxb + (size_t)m0*1536,
                   (const char*)wpb + (size_t)n0*1536,
                   As, Bs, tid, acc);

    const int l = tid & 63, w = tid >> 6;
    const int wr = w >> 1, wc = w & 1;
    const int rbase = m0 + wr*64 + ((l >> 4) << 2);
    #pragma unroll
    for (int mi = 0; mi < 4; ++mi)
        #pragma unroll
        for (int nj = 0; nj < 4; ++nj) {
            const int col = n0 + wc*64 + nj*16 + (l & 15);
            const float bv = bias[col];
            #pragma unroll
            for (int rr = 0; rr < 4; ++rr) {
                const int m = rbase + mi*16 + rr;
                out[(size_t)m*768 + col] = acc[mi][nj][rr] + bv;
            }
        }
}

// =======================================================================
// K2: K[n][m] = exp(10*cos(n,m) - 10) off-diag, 0 on diag. bf16 out.
// MFMA on qn bf16 tiles, XOR-swizzled LDS, fused exp epilogue.
// =======================================================================
__global__ __launch_bounds__(256)
void cost_kernel(const u16* __restrict__ qnbf, u16* __restrict__ Kmat)
{
    __shared__ u16 Qa[128*64];     // [row][64 k] bf16, slot s holds global slot s^(row&7)
    __shared__ u16 Qb[128*64];
    const int bh = blockIdx.y;
    const int tr = (blockIdx.x >> 1) * 128;
    const int tc = (blockIdx.x & 1) * 128;
    const char* qb = (const char*)(qnbf + (size_t)bh * 16384);
    const int tid = threadIdx.x;
    const int l = tid & 63, w = tid >> 6;
    const int wr = w >> 1, wc = w & 1;

    // ---- stage both tiles: 4 issues/wave/array; rows 8*(i*4+w)+(l>>3)
    {
        const int co = ((l & 7) ^ (l >> 3)) << 4;   // inverse-swizzled source slot
        const int rl = l >> 3;
        #pragma unroll
        for (int i = 0; i < 4; ++i) {
            const int ch = i*4 + w;                 // chunk 0..15
            gload_lds16(qb + (size_t)(tr + ch*8 + rl)*128 + co, (char*)Qa + ch*1024);
            gload_lds16(qb + (size_t)(tc + ch*8 + rl)*128 + co, (char*)Qb + ch*1024);
        }
    }
    __syncthreads();

    f32x4 acc[4][4];
    #pragma unroll
    for (int i = 0; i < 4; ++i)
        #pragma unroll
        for (int j = 0; j < 4; ++j) acc[i][j] = (f32x4){0.f,0.f,0.f,0.f};

    bf16x8 af[2][4], bfr[2][4];
    #pragma unroll
    for (int kk = 0; kk < 2; ++kk) {
        const int kb = kk*64 + ((l >> 4) << 4);
        #pragma unroll
        for (int f = 0; f < 4; ++f) {
            const int ra = wr*64 + f*16 + (l & 15);
            af[kk][f]  = *(const bf16x8*)((char*)Qa + ra*128 + (kb ^ ((ra & 7) << 4)));
            const int rb = wc*64 + f*16 + (l & 15);
            bfr[kk][f] = *(const bf16x8*)((char*)Qb + rb*128 + (kb ^ ((rb & 7) << 4)));
        }
    }
    #pragma unroll
    for (int mi = 0; mi < 4; ++mi)
        #pragma unroll
        for (int nj = 0; nj < 4; ++nj) {
            acc[mi][nj] = __builtin_amdgcn_mfma_f32_16x16x32_bf16(
                              af[0][mi], bfr[0][nj], acc[mi][nj], 0, 0, 0);
            acc[mi][nj] = __builtin_amdgcn_mfma_f32_16x16x32_bf16(
                              af[1][mi], bfr[1][nj], acc[mi][nj], 0, 0, 0);
        }

    // ---- epilogue: exp(10*s - 10), diag -> 0, bf16 store
    u16* Kb = Kmat + (size_t)bh * 65536;
    #pragma unroll
    for (int mi = 0; mi < 4; ++mi)
        #pragma unroll
        for (int nj = 0; nj < 4; ++nj) {
            const int gr0 = tr + wr*64 + mi*16 + ((l >> 4) << 2);
            const int gc  = tc + wc*64 + nj*16 + (l & 15);
            #pragma unroll
            for (int rr = 0; rr < 4; ++rr) {
                const int gr = gr0 + rr;
                const float s = acc[mi][nj][rr];
                const float km = (gr == gc) ? 0.f : __expf(fmaf(10.f, s, -10.f));
                Kb[(size_t)gr * 256 + gc] = f2bf(km);
            }
        }
}

// =======================================================================
// K3+K4 FUSED: Sinkhorn + softmax + PV in one kernel per (b,h), 512 thr.
// Phase 1 (sinkhorn): K in MFMA A-frags (wave w rows 32w..32w+31), 20
//   matvecs y=Kx on matrix cores (B = x broadcast), x'=(1/256)/y.
// Phase 2 (tmax): per-lane max u*K*v over frags, wave+block reduce.
// Phase 3 (P): p = exp(u*itmax*0.125 * K * v) computed ELEMENTWISE on the
//   frag layout (diag -> exp(0.125)), packed bf16 in place of kf. The A-frag
//   lane map (l&15 -> row, (l>>4)*8+j -> k) equals the B-frag map
//   (l&15 -> col, same k), so P-frags serve directly as MFMA B operands.
//   Row-sum psum: per-lane partial + shfl_xor(16,32) (4 lanes share a row).
// Phase 4 (PV): D[d][n] = sum_m Vt[d][m] * P[n][m] via mfma(Vt-frag, P-frag);
//   Vt [64][256] bf16 staged once, XOR-swizzled. Epilogue scales by 1/psum
//   (lane-local!) and writes ctx bf16 [b][n][768].
// =======================================================================
__global__ __launch_bounds__(512, 3)
void sinkhorn_attn_kernel(const u16* __restrict__ Kmat, const u16* __restrict__ vbfT,
                          u16* __restrict__ ctxc)
{
    __shared__ u16 Vt[64*256];       // 32 KB, slot s of row d holds global slot s^(d&7)
    __shared__ __align__(16) float ys[256];
    __shared__ __align__(16) float xv[256];
    __shared__ __align__(16) float usave[256];
    __shared__ __align__(16) u16   xbf[256];
    __shared__ float pmax[8];
    const int bh  = blockIdx.x;
    const int b_ = bh / 12, h_ = bh - b_*12;
    const int tid = threadIdx.x;
    const int l = tid & 63, w = tid >> 6;
    const int rowb = w * 32;
    const char* Kg = (const char*)(Kmat + (size_t)bh * 65536);

    // ---- stage Vt (32 KB): 4 issues x (512 thr x 16B); source pre-swizzled
    {
        const char* src = (const char*)(vbfT + (size_t)bh * 16384);
        char* dst = (char*)Vt;
        const int s = l & 31;
        #pragma unroll
        for (int i = 0; i < 4; ++i) {
            const int d = i*16 + w*2 + (l >> 5);
            gload_lds16(src + d*512 + ((s ^ (d & 7)) << 4), dst + i*8192 + w*1024);
        }
    }

    // ---- K frags: lane l holds K[rowb + t*16 + (l&15)][ks*32 + (l>>4)*8 + j]
    bf16x8 kf[2][8];
    {
        const char* kb0 = Kg + (size_t)(rowb + (l & 15)) * 512 + ((l >> 4) << 4);
        #pragma unroll
        for (int t = 0; t < 2; ++t)
            #pragma unroll
            for (int ks = 0; ks < 8; ++ks)
                kf[t][ks] = *(const bf16x8*)(kb0 + t*8192 + ks*64);
    }
    if (tid < 256) { xv[tid] = 1.0f; xbf[tid] = 0x3f80; }   // bf16(1.0)
    __syncthreads();                 // Vt + xv resident

    // ---- Phase 1: 20 half-iterations
    for (int it = 0; it < 20; ++it) {
        f32x4 a0 = {0.f,0.f,0.f,0.f}, a1 = {0.f,0.f,0.f,0.f};
        #pragma unroll
        for (int ks = 0; ks < 8; ++ks) {
            const bf16x8 xf = *(const bf16x8*)((const char*)xbf + ks*64 + ((l >> 4) << 4));
            a0 = __builtin_amdgcn_mfma_f32_16x16x32_bf16(kf[0][ks], xf, a0, 0, 0, 0);
            a1 = __builtin_amdgcn_mfma_f32_16x16x32_bf16(kf[1][ks], xf, a1, 0, 0, 0);
        }
        if ((l & 15) == 0) {                 // 4 lanes publish 2x4 rows each
            const int r0 = rowb + ((l >> 4) << 2);
            *(float4*)&ys[r0]      = make_float4(a0[0], a0[1], a0[2], a0[3]);
            *(float4*)&ys[r0 + 16] = make_float4(a1[0], a1[1], a1[2], a1[3]);
        }
        __syncthreads();
        if (tid < 256) {
            const float xn = 0.00390625f / ys[tid];   // (1/256)/y
            if (it == 18) usave[tid] = xn;            // u after 19th half-step
            xv[tid]  = xn;
            xbf[tid] = f2bf(xn);
        }
        __syncthreads();
    }

    // ---- Phase 2: Tmax = max u[n] K[n][m] v[m]
    {
        float mx = 0.f;
        const float u0 = usave[rowb + (l & 15)];
        const float u1 = usave[rowb + 16 + (l & 15)];
        #pragma unroll
        for (int ks = 0; ks < 8; ++ks) {
            const int mbase = ks*32 + ((l >> 4) << 3);
            const float4 va  = *(const float4*)&xv[mbase];
            const float4 vb4 = *(const float4*)&xv[mbase + 4];
            const float vv[8] = {va.x, va.y, va.z, va.w, vb4.x, vb4.y, vb4.z, vb4.w};
            #pragma unroll
            for (int j = 0; j < 8; ++j) {
                mx = fmaxf(mx, u0 * bf2f((u16)kf[0][ks][j]) * vv[j]);
                mx = fmaxf(mx, u1 * bf2f((u16)kf[1][ks][j]) * vv[j]);
            }
        }
        #pragma unroll
        for (int off = 32; off > 0; off >>= 1) mx = fmaxf(mx, __shfl_xor(mx, off));
        if (l == 0) pmax[w] = mx;
    }
    __syncthreads();
    float tm = pmax[0];
    #pragma unroll
    for (int i = 1; i < 8; ++i) tm = fmaxf(tm, pmax[i]);
    const float itmax = 1.0f / tm;

    // ---- Phase 3: P = exp(an*K*v) elementwise on frags (in place), psum
    float psum[2] = {0.f, 0.f};
    {
        const float an[2] = { usave[rowb + (l & 15)] * itmax * 0.125f,
                              usave[rowb + 16 + (l & 15)] * itmax * 0.125f };
        #pragma unroll
        for (int t = 0; t < 2; ++t) {
            const int rown = rowb + t*16 + (l & 15);
            #pragma unroll
            for (int ks = 0; ks < 8; ++ks) {
                const int mbase = ks*32 + ((l >> 4) << 3);
                const float4 va  = *(const float4*)&xv[mbase];
                const float4 vb4 = *(const float4*)&xv[mbase + 4];
                const float vv[8] = {va.x, va.y, va.z, va.w, vb4.x, vb4.y, vb4.z, vb4.w};
                float p[8];
                #pragma unroll
                for (int j = 0; j < 8; ++j)
                    p[j] = __expf(an[t] * bf2f((u16)kf[t][ks][j]) * vv[j]);
                const int dj = rown - mbase;
                if (dj >= 0 && dj < 8) p[dj] = 1.13314845f;     // exp(0.125)
                psum[t] += ((p[0]+p[1]) + (p[2]+p[3])) + ((p[4]+p[5]) + (p[6]+p[7]));
                bf16x8 pf;
                #pragma unroll
                for (int j = 0; j < 8; ++j) pf[j] = (short)f2bf(p[j]);
                kf[t][ks] = pf;                                  // overwrite K
            }
            psum[t] += __shfl_xor(psum[t], 16);
            psum[t] += __shfl_xor(psum[t], 32);                  // 4 lanes/row summed
        }
    }

    // ---- Phase 4: PV. D[d][n] += Vt-frag x P-frag
    f32x4 acc[2][4];
    #pragma unroll
    for (int t = 0; t < 2; ++t)
        #pragma unroll
        for (int dt = 0; dt < 4; ++dt) acc[t][dt] = (f32x4){0.f,0.f,0.f,0.f};
    #pragma unroll
    for (int ks = 0; ks < 8; ++ks) {
        bf16x8 vf[4];
        const int bc = ks*64 + ((l >> 4) << 4);
        #pragma unroll
        for (int dt = 0; dt < 4; ++dt) {
            const int d = dt*16 + (l & 15);
            vf[dt] = *(const bf16x8*)((char*)Vt + d*512 + (bc ^ ((d & 7) << 4)));
        }
        #pragma unroll
        for (int t = 0; t < 2; ++t)
            #pragma unroll
            for (int dt = 0; dt < 4; ++dt)
                acc[t][dt] = __builtin_amdgcn_mfma_f32_16x16x32_bf16(
                                 vf[dt], kf[t][ks], acc[t][dt], 0, 0, 0);
    }

    // ---- epilogue: D col = n (lane's own psum!), D rows = d; ctx bf16 write
    u16* outp = ctxc + ((size_t)b_*256)*768 + h_*64;
    #pragma unroll
    for (int t = 0; t < 2; ++t) {
        const int n = rowb + t*16 + (l & 15);
        const float is = 1.0f / psum[t];
        #pragma unroll
        for (int dt = 0; dt < 4; ++dt) {
            const int d0 = dt*16 + ((l >> 4) << 2);
            uint2 o = make_uint2(pack2bf(acc[t][dt][0]*is, acc[t][dt][1]*is),
                                 pack2bf(acc[t][dt][2]*is, acc[t][dt][3]*is));
            *(uint2*)&outp[(size_t)n*768 + d0] = o;
        }
    }
}

// =======================================================================
extern "C" void kernel_launch(void* const* d_in, const int* in_sizes, int n_in,
                              void* d_out, int out_size, void* d_ws, size_t ws_size,
                              hipStream_t stream)
{
    (void)in_sizes; (void)n_in; (void)out_size; (void)ws_size;
    const float* x      = (const float*)d_in[0];
    const float* w_qkv  = (const float*)d_in[1];
    const float* w_proj = (const float*)d_in[2];
    const float* b_proj = (const float*)d_in[3];
    float* out = (float*)d_out;

    char* w = (char*)d_ws;
    // workspace layout (bytes):
    u16*   xbf  = (u16*)  (w);                     //  25,165,824  x bf16 [16384][768]
    u16*   wqv  = (u16*)  (w + 25165824);          //   2,359,296  w q+v rows bf16 [1536][768]
    u16*   wpb  = (u16*)  (w + 27525120);          //   1,179,648  w_proj bf16 [768][768]
    u16*   qnbf = (u16*)  (w + 28704768);          //  25,165,824  qn bf16 [768][256][64]
    u16*   vbfT = (u16*)  (w + 79036416);          //  25,165,824  v^T bf16 [768][64][256]
    u16*   ctxc = (u16*)  (w + 104202240);         //  25,165,824  ctx bf16 [64][256][768]
    u16*   Km   = (u16*)  (w + 130944000);         // 100,663,296  K bf16 [768][256][256]
    // total ~231.6 MB

    conv_bf16          <<<dim3(6144),    256, 0, stream>>>(x, xbf, 1572864);
    conv_wqv           <<<dim3(576),     256, 0, stream>>>(w_qkv, wqv);
    conv_bf16          <<<dim3(288),     256, 0, stream>>>(w_proj, wpb, 73728);
    gemm_qkv_mfma      <<<dim3(128, 12), 256, 0, stream>>>(xbf, wqv, qnbf, vbfT);
    cost_kernel        <<<dim3(4, 768),  256, 0, stream>>>(qnbf, Km);
    sinkhorn_attn_kernel<<<dim3(768),    512, 0, stream>>>(Km, vbfT, ctxc);
    gemm_proj_mfma     <<<dim3(128, 6),  256, 0, stream>>>(ctxc, wpb, b_proj, out);
}

// Round 9
// 230.216 us; speedup vs baseline: 1.1402x; 1.1402x over previous
//
#include <hip/hip_runtime.h>

typedef unsigned short u16;
typedef unsigned int   u32;
typedef __attribute__((ext_vector_type(8))) short bf16x8;
typedef __attribute__((ext_vector_type(4))) float f32x4;

// ---------- bf16 helpers (manual, RNE) ----------
__device__ __forceinline__ u16 f2bf(float f) {
    u32 u = __float_as_uint(f);
    u += 0x7fffu + ((u >> 16) & 1u);
    return (u16)(u >> 16);
}
__device__ __forceinline__ float bf2f(u16 s) {
    return __uint_as_float(((u32)s) << 16);
}
__device__ __forceinline__ u32 pack2bf(float f0, float f1) {
    return (u32)f2bf(f0) | ((u32)f2bf(f1) << 16);
}

__device__ __forceinline__ void gload_lds16(const void* g, void* l) {
    __builtin_amdgcn_global_load_lds(
        (const __attribute__((address_space(1))) u32*)g,
        (__attribute__((address_space(3))) u32*)l, 16, 0, 0);
}

// =======================================================================
// fp32 -> bf16 converters
// =======================================================================
__global__ __launch_bounds__(256)
void conv_bf16(const float* __restrict__ src, u16* __restrict__ dst, int n8)
{
    const int i = blockIdx.x * 256 + threadIdx.x;   // 8 elements per thread
    if (i < n8) {
        const float4 a = ((const float4*)src)[2*i];
        const float4 b = ((const float4*)src)[2*i + 1];
        ((uint4*)dst)[i] = make_uint4(pack2bf(a.x,a.y), pack2bf(a.z,a.w),
                                      pack2bf(b.x,b.y), pack2bf(b.z,b.w));
    }
}

// w_qkv [2304][768]: keep q rows 0..767 and v rows 1536..2303 -> wqv [1536][768]
__global__ __launch_bounds__(256)
void conv_wqv(const float* __restrict__ w, u16* __restrict__ dst)
{
    const int i = blockIdx.x * 256 + threadIdx.x;   // chunk of 8, 96 chunks/row
    const int row = i / 96;
    const int cc  = (i - row * 96) * 8;
    const int srow = row + (row >= 768 ? 768 : 0);
    const float4 a = *(const float4*)&w[(size_t)srow*768 + cc];
    const float4 b = *(const float4*)&w[(size_t)srow*768 + cc + 4];
    *(uint4*)&dst[(size_t)row*768 + cc] =
        make_uint4(pack2bf(a.x,a.y), pack2bf(a.z,a.w), pack2bf(b.x,b.y), pack2bf(b.z,b.w));
}

// =======================================================================
// Shared MFMA GEMM core: C[128x128] tile, K=768, bf16 A[.,768] x B[.,768]^T.
// BK=64, 4 waves (2x2), 16x16x32 MFMA, global_load_lds + XOR-swizzled LDS.
// =======================================================================
__device__ __forceinline__ void mfma_gemm_core(
    const char* __restrict__ Arow0,   // &A[m0][0] as bytes (row stride 1536)
    const char* __restrict__ Brow0,   // &B[n0][0] as bytes
    u16* As, u16* Bs, const int tid, f32x4 acc[4][4])
{
    const int l  = tid & 63, w = tid >> 6;
    const int wr = w >> 1,  wc = w & 1;
    char* Asb = (char*)As;
    char* Bsb = (char*)Bs;
    const int co = 16 * ((l & 7) ^ (l >> 3));       // swizzled global byte col
    const size_t rstep = (size_t)(l >> 3) * 1536;
    const int rsw = (l & 7) << 4;                   // read-side XOR

    for (int k0 = 0; k0 < 1536; k0 += 128) {        // 12 K-steps of 64 bf16
        #pragma unroll
        for (int i = 0; i < 4; ++i) {
            const int rb = i*32 + w*8;
            gload_lds16(Arow0 + (size_t)rb*1536 + rstep + k0 + co, Asb + i*4096 + w*1024);
            gload_lds16(Brow0 + (size_t)rb*1536 + rstep + k0 + co, Bsb + i*4096 + w*1024);
        }
        __syncthreads();
        bf16x8 af[2][4], bfr[2][4];
        #pragma unroll
        for (int kk = 0; kk < 2; ++kk) {
            const int coff = (kk*64 + ((l >> 4) << 4)) ^ rsw;
            #pragma unroll
            for (int mi = 0; mi < 4; ++mi) {
                const int rowA = wr*64 + mi*16 + (l & 15);
                af[kk][mi]  = *(const bf16x8*)(Asb + rowA*128 + coff);
                const int rowB = wc*64 + mi*16 + (l & 15);
                bfr[kk][mi] = *(const bf16x8*)(Bsb + rowB*128 + coff);
            }
        }
        #pragma unroll
        for (int mi = 0; mi < 4; ++mi)
            #pragma unroll
            for (int nj = 0; nj < 4; ++nj) {
                acc[mi][nj] = __builtin_amdgcn_mfma_f32_16x16x32_bf16(
                                  af[0][mi], bfr[0][nj], acc[mi][nj], 0, 0, 0);
                acc[mi][nj] = __builtin_amdgcn_mfma_f32_16x16x32_bf16(
                                  af[1][mi], bfr[1][nj], acc[mi][nj], 0, 0, 0);
            }
        __syncthreads();
    }
}

// =======================================================================
// K0: q/v projection + FUSED q-normalize. xbf [16384][768], wqv [1536][768].
// bj<6 -> q cols: each wave's 64 cols = one head (h = 2bj+wc); row-norm via
// 16-lane shfl_xor reduce over nj-frags; writes qn bf16 [bh][n][64] direct.
// bj>=6 -> v cols, written TRANSPOSED as vbfT [bh][d][m] bf16.
// =======================================================================
__global__ __launch_bounds__(256)
void gemm_qkv_mfma(const u16* __restrict__ xbf, const u16* __restrict__ wqv,
                   u16* __restrict__ qnbf, u16* __restrict__ vbfT)
{
    __shared__ u16 As[128*64];
    __shared__ u16 Bs[128*64];
    const int m0 = blockIdx.x * 128;
    const int bj = blockIdx.y;
    const int tid = threadIdx.x;
    f32x4 acc[4][4];
    #pragma unroll
    for (int i = 0; i < 4; ++i)
        #pragma unroll
        for (int j = 0; j < 4; ++j) acc[i][j] = (f32x4){0.f,0.f,0.f,0.f};

    mfma_gemm_core((const char*)xbf + (size_t)m0*1536,
                   (const char*)wqv + (size_t)bj*128*1536,
                   As, Bs, tid, acc);

    const int l = tid & 63, w = tid >> 6;
    const int wr = w >> 1, wc = w & 1;
    const int rbase = m0 + wr*64 + ((l >> 4) << 2);
    if (bj < 6) {
        const int h = 2*bj + wc;                   // wave's 64 cols = head h
        #pragma unroll
        for (int mi = 0; mi < 4; ++mi)
            #pragma unroll
            for (int rr = 0; rr < 4; ++rr) {
                float s =      acc[mi][0][rr]*acc[mi][0][rr];
                s = fmaf(acc[mi][1][rr], acc[mi][1][rr], s);
                s = fmaf(acc[mi][2][rr], acc[mi][2][rr], s);
                s = fmaf(acc[mi][3][rr], acc[mi][3][rr], s);
                #pragma unroll
                for (int off = 1; off < 16; off <<= 1) s += __shfl_xor(s, off);
                const float inv = 1.0f / (sqrtf(s) + 1e-8f);
                const int m = rbase + mi*16 + rr;
                const int b_ = m >> 8, n_ = m & 255;
                u16* row = qnbf + ((((size_t)b_*12 + h) << 8) + n_)*64;
                #pragma unroll
                for (int nj = 0; nj < 4; ++nj)
                    row[nj*16 + (l & 15)] = f2bf(acc[mi][nj][rr] * inv);
            }
    } else {
        const int colb = (bj - 6)*128 + wc*64;
        #pragma unroll
        for (int mi = 0; mi < 4; ++mi)
            #pragma unroll
            for (int nj = 0; nj < 4; ++nj) {
                const int col = colb + nj*16 + (l & 15);
                const int h = col >> 6, d = col & 63;
                const int m = rbase + mi*16;        // rows m..m+3 (consecutive)
                const int b_ = m >> 8, n_ = m & 255;
                uint2 o = make_uint2(pack2bf(acc[mi][nj][0], acc[mi][nj][1]),
                                     pack2bf(acc[mi][nj][2], acc[mi][nj][3]));
                *(uint2*)&vbfT[(((size_t)b_*12 + h)*64 + d)*256 + n_] = o;
            }
    }
}

// =======================================================================
// K5: out = ctx @ w_proj^T + b_proj. ctxb [16384][768] bf16, wpb [768][768] bf16.
// =======================================================================
__global__ __launch_bounds__(256)
void gemm_proj_mfma(const u16* __restrict__ ctxb, const u16* __restrict__ wpb,
                    const float* __restrict__ bias, float* __restrict__ out)
{
    __shared__ u16 As[128*64];
    __shared__ u16 Bs[128*64];
    const int m0 = blockIdx.x * 128;
    const int n0 = blockIdx.y * 128;
    const int tid = threadIdx.x;
    f32x4 acc[4][4];
    #pragma unroll
    for (int i = 0; i < 4; ++i)
        #pragma unroll
        for (int j = 0; j < 4; ++j) acc[i][j] = (f32x4){0.f,0.f,0.f,0.f};

    mfma_gemm_core((const char*)ctxb + (size_t)m0*1536,
                   (const char*)wpb + (size_t)n0*1536,
                   As, Bs, tid, acc);

    const int l = tid & 63, w = tid >> 6;
    const int wr = w >> 1, wc = w & 1;
    const int rbase = m0 + wr*64 + ((l >> 4) << 2);
    #pragma unroll
    for (int mi = 0; mi < 4; ++mi)
        #pragma unroll
        for (int nj = 0; nj < 4; ++nj) {
            const int col = n0 + wc*64 + nj*16 + (l & 15);
            const float bv = bias[col];
            #pragma unroll
            for (int rr = 0; rr < 4; ++rr) {
                const int m = rbase + mi*16 + rr;
                out[(size_t)m*768 + col] = acc[mi][nj][rr] + bv;
            }
        }
}

// =======================================================================
// K2: K[n][m] = exp(10*cos(n,m) - 10) off-diag, 0 on diag. bf16 out.
// MFMA on qn bf16 tiles, XOR-swizzled LDS, fused exp epilogue.
// =======================================================================
__global__ __launch_bounds__(256)
void cost_kernel(const u16* __restrict__ qnbf, u16* __restrict__ Kmat)
{
    __shared__ u16 Qa[128*64];     // [row][64 k] bf16, slot s holds global slot s^(row&7)
    __shared__ u16 Qb[128*64];
    const int bh = blockIdx.y;
    const int tr = (blockIdx.x >> 1) * 128;
    const int tc = (blockIdx.x & 1) * 128;
    const char* qb = (const char*)(qnbf + (size_t)bh * 16384);
    const int tid = threadIdx.x;
    const int l = tid & 63, w = tid >> 6;
    const int wr = w >> 1, wc = w & 1;

    // ---- stage both tiles: 4 issues/wave/array; rows 8*(i*4+w)+(l>>3)
    {
        const int co = ((l & 7) ^ (l >> 3)) << 4;   // inverse-swizzled source slot
        const int rl = l >> 3;
        #pragma unroll
        for (int i = 0; i < 4; ++i) {
            const int ch = i*4 + w;                 // chunk 0..15
            gload_lds16(qb + (size_t)(tr + ch*8 + rl)*128 + co, (char*)Qa + ch*1024);
            gload_lds16(qb + (size_t)(tc + ch*8 + rl)*128 + co, (char*)Qb + ch*1024);
        }
    }
    __syncthreads();

    f32x4 acc[4][4];
    #pragma unroll
    for (int i = 0; i < 4; ++i)
        #pragma unroll
        for (int j = 0; j < 4; ++j) acc[i][j] = (f32x4){0.f,0.f,0.f,0.f};

    bf16x8 af[2][4], bfr[2][4];
    #pragma unroll
    for (int kk = 0; kk < 2; ++kk) {
        const int kb = kk*64 + ((l >> 4) << 4);
        #pragma unroll
        for (int f = 0; f < 4; ++f) {
            const int ra = wr*64 + f*16 + (l & 15);
            af[kk][f]  = *(const bf16x8*)((char*)Qa + ra*128 + (kb ^ ((ra & 7) << 4)));
            const int rb = wc*64 + f*16 + (l & 15);
            bfr[kk][f] = *(const bf16x8*)((char*)Qb + rb*128 + (kb ^ ((rb & 7) << 4)));
        }
    }
    #pragma unroll
    for (int mi = 0; mi < 4; ++mi)
        #pragma unroll
        for (int nj = 0; nj < 4; ++nj) {
            acc[mi][nj] = __builtin_amdgcn_mfma_f32_16x16x32_bf16(
                              af[0][mi], bfr[0][nj], acc[mi][nj], 0, 0, 0);
            acc[mi][nj] = __builtin_amdgcn_mfma_f32_16x16x32_bf16(
                              af[1][mi], bfr[1][nj], acc[mi][nj], 0, 0, 0);
        }

    // ---- epilogue: exp(10*s - 10), diag -> 0, bf16 store
    u16* Kb = Kmat + (size_t)bh * 65536;
    #pragma unroll
    for (int mi = 0; mi < 4; ++mi)
        #pragma unroll
        for (int nj = 0; nj < 4; ++nj) {
            const int gr0 = tr + wr*64 + mi*16 + ((l >> 4) << 2);
            const int gc  = tc + wc*64 + nj*16 + (l & 15);
            #pragma unroll
            for (int rr = 0; rr < 4; ++rr) {
                const int gr = gr0 + rr;
                const float s = acc[mi][nj][rr];
                const float km = (gr == gc) ? 0.f : __expf(fmaf(10.f, s, -10.f));
                Kb[(size_t)gr * 256 + gc] = f2bf(km);
            }
        }
}

// =======================================================================
// K3+K4 FUSED (v2, spill-fixed): Sinkhorn + softmax + PV, 512 thr/(b,h).
// Phase 1: K in MFMA A-frags, 20 matvecs y=Kx on matrix cores.
// Phase 2: Tmax reduce.
// Phase 3+4 merged, per t-half then per ks: build P-frag from kf[t][ks]
//   elementwise (exp, diag override), CONSUME it immediately in 4 MFMAs
//   (D[d][n] += Vt-frag x P-frag) - P never stored, kf never overwritten,
//   acc only 4 f32x4 live (per-t epilogue). Peak ~115 VGPR -> no spill.
// A-frag lane map == B-frag lane map (l&15 -> row/col, (l>>4)*8+j -> k),
// so P-frags are valid B operands. D col = n -> psum is lane-local.
// =======================================================================
__global__ __launch_bounds__(512, 2)
void sinkhorn_attn_kernel(const u16* __restrict__ Kmat, const u16* __restrict__ vbfT,
                          u16* __restrict__ ctxc)
{
    __shared__ u16 Vt[64*256];       // 32 KB, slot s of row d holds global slot s^(d&7)
    __shared__ __align__(16) float ys[256];
    __shared__ __align__(16) float xv[256];
    __shared__ __align__(16) float usave[256];
    __shared__ __align__(16) u16   xbf[256];
    __shared__ float pmax[8];
    const int bh  = blockIdx.x;
    const int b_ = bh / 12, h_ = bh - b_*12;
    const int tid = threadIdx.x;
    const int l = tid & 63, w = tid >> 6;
    const int rowb = w * 32;
    const char* Kg = (const char*)(Kmat + (size_t)bh * 65536);

    // ---- stage Vt (32 KB): 4 issues x (512 thr x 16B); source pre-swizzled
    {
        const char* src = (const char*)(vbfT + (size_t)bh * 16384);
        char* dst = (char*)Vt;
        const int s = l & 31;
        #pragma unroll
        for (int i = 0; i < 4; ++i) {
            const int d = i*16 + w*2 + (l >> 5);
            gload_lds16(src + d*512 + ((s ^ (d & 7)) << 4), dst + i*8192 + w*1024);
        }
    }

    // ---- K frags: lane l holds K[rowb + t*16 + (l&15)][ks*32 + (l>>4)*8 + j]
    bf16x8 kf[2][8];
    {
        const char* kb0 = Kg + (size_t)(rowb + (l & 15)) * 512 + ((l >> 4) << 4);
        #pragma unroll
        for (int t = 0; t < 2; ++t)
            #pragma unroll
            for (int ks = 0; ks < 8; ++ks)
                kf[t][ks] = *(const bf16x8*)(kb0 + t*8192 + ks*64);
    }
    if (tid < 256) { xv[tid] = 1.0f; xbf[tid] = 0x3f80; }   // bf16(1.0)
    __syncthreads();                 // Vt + xv resident

    // ---- Phase 1: 20 half-iterations
    for (int it = 0; it < 20; ++it) {
        f32x4 a0 = {0.f,0.f,0.f,0.f}, a1 = {0.f,0.f,0.f,0.f};
        #pragma unroll
        for (int ks = 0; ks < 8; ++ks) {
            const bf16x8 xf = *(const bf16x8*)((const char*)xbf + ks*64 + ((l >> 4) << 4));
            a0 = __builtin_amdgcn_mfma_f32_16x16x32_bf16(kf[0][ks], xf, a0, 0, 0, 0);
            a1 = __builtin_amdgcn_mfma_f32_16x16x32_bf16(kf[1][ks], xf, a1, 0, 0, 0);
        }
        if ((l & 15) == 0) {                 // 4 lanes publish 2x4 rows each
            const int r0 = rowb + ((l >> 4) << 2);
            *(float4*)&ys[r0]      = make_float4(a0[0], a0[1], a0[2], a0[3]);
            *(float4*)&ys[r0 + 16] = make_float4(a1[0], a1[1], a1[2], a1[3]);
        }
        __syncthreads();
        if (tid < 256) {
            const float xn = 0.00390625f / ys[tid];   // (1/256)/y
            if (it == 18) usave[tid] = xn;            // u after 19th half-step
            xv[tid]  = xn;
            xbf[tid] = f2bf(xn);
        }
        __syncthreads();
    }

    // ---- Phase 2: Tmax = max u[n] K[n][m] v[m]
    {
        float mx = 0.f;
        const float u0 = usave[rowb + (l & 15)];
        const float u1 = usave[rowb + 16 + (l & 15)];
        #pragma unroll
        for (int ks = 0; ks < 8; ++ks) {
            const int mbase = ks*32 + ((l >> 4) << 3);
            const float4 va  = *(const float4*)&xv[mbase];
            const float4 vb4 = *(const float4*)&xv[mbase + 4];
            const float vv[8] = {va.x, va.y, va.z, va.w, vb4.x, vb4.y, vb4.z, vb4.w};
            #pragma unroll
            for (int j = 0; j < 8; ++j) {
                mx = fmaxf(mx, u0 * bf2f((u16)kf[0][ks][j]) * vv[j]);
                mx = fmaxf(mx, u1 * bf2f((u16)kf[1][ks][j]) * vv[j]);
            }
        }
        #pragma unroll
        for (int off = 32; off > 0; off >>= 1) mx = fmaxf(mx, __shfl_xor(mx, off));
        if (l == 0) pmax[w] = mx;
    }
    __syncthreads();
    float tm = pmax[0];
    #pragma unroll
    for (int i = 1; i < 8; ++i) tm = fmaxf(tm, pmax[i]);
    const float itmax = 1.0f / tm;

    // ---- Phase 3+4 merged: per t-half: P frag -> immediate PV MFMA
    u16* outp = ctxc + ((size_t)b_*256)*768 + h_*64;
    #pragma unroll
    for (int t = 0; t < 2; ++t) {
        const int rown = rowb + t*16 + (l & 15);
        const float an = usave[rown] * itmax * 0.125f;
        float psum = 0.f;
        f32x4 acc0 = {0.f,0.f,0.f,0.f}, acc1 = {0.f,0.f,0.f,0.f};
        f32x4 acc2 = {0.f,0.f,0.f,0.f}, acc3 = {0.f,0.f,0.f,0.f};
        #pragma unroll
        for (int ks = 0; ks < 8; ++ks) {
            const int mbase = ks*32 + ((l >> 4) << 3);
            const float4 va  = *(const float4*)&xv[mbase];
            const float4 vb4 = *(const float4*)&xv[mbase + 4];
            const float vv[8] = {va.x, va.y, va.z, va.w, vb4.x, vb4.y, vb4.z, vb4.w};
            float p[8];
            #pragma unroll
            for (int j = 0; j < 8; ++j)
                p[j] = __expf(an * bf2f((u16)kf[t][ks][j]) * vv[j]);
            const int dj = rown - mbase;
            if (dj >= 0 && dj < 8) p[dj] = 1.13314845f;     // exp(0.125)
            psum += ((p[0]+p[1]) + (p[2]+p[3])) + ((p[4]+p[5]) + (p[6]+p[7]));
            bf16x8 pf;
            #pragma unroll
            for (int j = 0; j < 8; ++j) pf[j] = (short)f2bf(p[j]);
            const int bc = ks*64 + ((l >> 4) << 4);
            {
                const int d = (l & 15);
                const bf16x8 vf = *(const bf16x8*)((char*)Vt + d*512 + (bc ^ ((d & 7) << 4)));
                acc0 = __builtin_amdgcn_mfma_f32_16x16x32_bf16(vf, pf, acc0, 0, 0, 0);
            }
            {
                const int d = 16 + (l & 15);
                const bf16x8 vf = *(const bf16x8*)((char*)Vt + d*512 + (bc ^ ((d & 7) << 4)));
                acc1 = __builtin_amdgcn_mfma_f32_16x16x32_bf16(vf, pf, acc1, 0, 0, 0);
            }
            {
                const int d = 32 + (l & 15);
                const bf16x8 vf = *(const bf16x8*)((char*)Vt + d*512 + (bc ^ ((d & 7) << 4)));
                acc2 = __builtin_amdgcn_mfma_f32_16x16x32_bf16(vf, pf, acc2, 0, 0, 0);
            }
            {
                const int d = 48 + (l & 15);
                const bf16x8 vf = *(const bf16x8*)((char*)Vt + d*512 + (bc ^ ((d & 7) << 4)));
                acc3 = __builtin_amdgcn_mfma_f32_16x16x32_bf16(vf, pf, acc3, 0, 0, 0);
            }
        }
        psum += __shfl_xor(psum, 16);
        psum += __shfl_xor(psum, 32);                  // 4 lanes/row summed
        const float is = 1.0f / psum;
        const int d0 = (l >> 4) << 2;
        uint2 o0 = make_uint2(pack2bf(acc0[0]*is, acc0[1]*is), pack2bf(acc0[2]*is, acc0[3]*is));
        uint2 o1 = make_uint2(pack2bf(acc1[0]*is, acc1[1]*is), pack2bf(acc1[2]*is, acc1[3]*is));
        uint2 o2 = make_uint2(pack2bf(acc2[0]*is, acc2[1]*is), pack2bf(acc2[2]*is, acc2[3]*is));
        uint2 o3 = make_uint2(pack2bf(acc3[0]*is, acc3[1]*is), pack2bf(acc3[2]*is, acc3[3]*is));
        u16* orow = outp + (size_t)rown*768;
        *(uint2*)&orow[d0]      = o0;
        *(uint2*)&orow[16 + d0] = o1;
        *(uint2*)&orow[32 + d0] = o2;
        *(uint2*)&orow[48 + d0] = o3;
    }
}

// =======================================================================
extern "C" void kernel_launch(void* const* d_in, const int* in_sizes, int n_in,
                              void* d_out, int out_size, void* d_ws, size_t ws_size,
                              hipStream_t stream)
{
    (void)in_sizes; (void)n_in; (void)out_size; (void)ws_size;
    const float* x      = (const float*)d_in[0];
    const float* w_qkv  = (const float*)d_in[1];
    const float* w_proj = (const float*)d_in[2];
    const float* b_proj = (const float*)d_in[3];
    float* out = (float*)d_out;

    char* w = (char*)d_ws;
    // workspace layout (bytes):
    u16*   xbf  = (u16*)  (w);                     //  25,165,824  x bf16 [16384][768]
    u16*   wqv  = (u16*)  (w + 25165824);          //   2,359,296  w q+v rows bf16 [1536][768]
    u16*   wpb  = (u16*)  (w + 27525120);          //   1,179,648  w_proj bf16 [768][768]
    u16*   qnbf = (u16*)  (w + 28704768);          //  25,165,824  qn bf16 [768][256][64]
    u16*   vbfT = (u16*)  (w + 79036416);          //  25,165,824  v^T bf16 [768][64][256]
    u16*   ctxc = (u16*)  (w + 104202240);         //  25,165,824  ctx bf16 [64][256][768]
    u16*   Km   = (u16*)  (w + 130944000);         // 100,663,296  K bf16 [768][256][256]
    // total ~231.6 MB

    conv_bf16           <<<dim3(6144),    256, 0, stream>>>(x, xbf, 1572864);
    conv_wqv            <<<dim3(576),     256, 0, stream>>>(w_qkv, wqv);
    conv_bf16           <<<dim3(288),     256, 0, stream>>>(w_proj, wpb, 73728);
    gemm_qkv_mfma       <<<dim3(128, 12), 256, 0, stream>>>(xbf, wqv, qnbf, vbfT);
    cost_kernel         <<<dim3(4, 768),  256, 0, stream>>>(qnbf, Km);
    sinkhorn_attn_kernel<<<dim3(768),     512, 0, stream>>>(Km, vbfT, ctxc);
    gemm_proj_mfma      <<<dim3(128, 6),  256, 0, stream>>>(ctxc, wpb, b_proj, out);
}

// Round 10
// 226.664 us; speedup vs baseline: 1.1581x; 1.0157x over previous
//
#include <hip/hip_runtime.h>

typedef unsigned short u16;
typedef unsigned int   u32;
typedef __attribute__((ext_vector_type(8))) short bf16x8;
typedef __attribute__((ext_vector_type(4))) float f32x4;

// ---------- bf16 helpers (manual, RNE) ----------
__device__ __forceinline__ u16 f2bf(float f) {
    u32 u = __float_as_uint(f);
    u += 0x7fffu + ((u >> 16) & 1u);
    return (u16)(u >> 16);
}
__device__ __forceinline__ float bf2f(u16 s) {
    return __uint_as_float(((u32)s) << 16);
}
__device__ __forceinline__ u32 pack2bf(float f0, float f1) {
    return (u32)f2bf(f0) | ((u32)f2bf(f1) << 16);
}

__device__ __forceinline__ void gload_lds16(const void* g, void* l) {
    __builtin_amdgcn_global_load_lds(
        (const __attribute__((address_space(1))) u32*)g,
        (__attribute__((address_space(3))) u32*)l, 16, 0, 0);
}

// =======================================================================
// fp32 -> bf16 converters
// =======================================================================
__global__ __launch_bounds__(256)
void conv_bf16(const float* __restrict__ src, u16* __restrict__ dst, int n8)
{
    const int i = blockIdx.x * 256 + threadIdx.x;   // 8 elements per thread
    if (i < n8) {
        const float4 a = ((const float4*)src)[2*i];
        const float4 b = ((const float4*)src)[2*i + 1];
        ((uint4*)dst)[i] = make_uint4(pack2bf(a.x,a.y), pack2bf(a.z,a.w),
                                      pack2bf(b.x,b.y), pack2bf(b.z,b.w));
    }
}

// w_qkv [2304][768]: keep q rows 0..767 and v rows 1536..2303 -> wqv [1536][768]
__global__ __launch_bounds__(256)
void conv_wqv(const float* __restrict__ w, u16* __restrict__ dst)
{
    const int i = blockIdx.x * 256 + threadIdx.x;   // chunk of 8, 96 chunks/row
    const int row = i / 96;
    const int cc  = (i - row * 96) * 8;
    const int srow = row + (row >= 768 ? 768 : 0);
    const float4 a = *(const float4*)&w[(size_t)srow*768 + cc];
    const float4 b = *(const float4*)&w[(size_t)srow*768 + cc + 4];
    *(uint4*)&dst[(size_t)row*768 + cc] =
        make_uint4(pack2bf(a.x,a.y), pack2bf(a.z,a.w), pack2bf(b.x,b.y), pack2bf(b.z,b.w));
}

// =======================================================================
// Shared MFMA GEMM core: C[128x128] tile, K=768, bf16 A[.,768] x B[.,768]^T.
// BK=64, 4 waves (2x2), 16x16x32 MFMA, global_load_lds + XOR-swizzled LDS.
// =======================================================================
__device__ __forceinline__ void mfma_gemm_core(
    const char* __restrict__ Arow0,   // &A[m0][0] as bytes (row stride 1536)
    const char* __restrict__ Brow0,   // &B[n0][0] as bytes
    u16* As, u16* Bs, const int tid, f32x4 acc[4][4])
{
    const int l  = tid & 63, w = tid >> 6;
    const int wr = w >> 1,  wc = w & 1;
    char* Asb = (char*)As;
    char* Bsb = (char*)Bs;
    const int co = 16 * ((l & 7) ^ (l >> 3));       // swizzled global byte col
    const size_t rstep = (size_t)(l >> 3) * 1536;
    const int rsw = (l & 7) << 4;                   // read-side XOR

    for (int k0 = 0; k0 < 1536; k0 += 128) {        // 12 K-steps of 64 bf16
        #pragma unroll
        for (int i = 0; i < 4; ++i) {
            const int rb = i*32 + w*8;
            gload_lds16(Arow0 + (size_t)rb*1536 + rstep + k0 + co, Asb + i*4096 + w*1024);
            gload_lds16(Brow0 + (size_t)rb*1536 + rstep + k0 + co, Bsb + i*4096 + w*1024);
        }
        __syncthreads();
        bf16x8 af[2][4], bfr[2][4];
        #pragma unroll
        for (int kk = 0; kk < 2; ++kk) {
            const int coff = (kk*64 + ((l >> 4) << 4)) ^ rsw;
            #pragma unroll
            for (int mi = 0; mi < 4; ++mi) {
                const int rowA = wr*64 + mi*16 + (l & 15);
                af[kk][mi]  = *(const bf16x8*)(Asb + rowA*128 + coff);
                const int rowB = wc*64 + mi*16 + (l & 15);
                bfr[kk][mi] = *(const bf16x8*)(Bsb + rowB*128 + coff);
            }
        }
        #pragma unroll
        for (int mi = 0; mi < 4; ++mi)
            #pragma unroll
            for (int nj = 0; nj < 4; ++nj) {
                acc[mi][nj] = __builtin_amdgcn_mfma_f32_16x16x32_bf16(
                                  af[0][mi], bfr[0][nj], acc[mi][nj], 0, 0, 0);
                acc[mi][nj] = __builtin_amdgcn_mfma_f32_16x16x32_bf16(
                                  af[1][mi], bfr[1][nj], acc[mi][nj], 0, 0, 0);
            }
        __syncthreads();
    }
}

// =======================================================================
// K0: q/v projection + FUSED q-normalize. xbf [16384][768], wqv [1536][768].
// bj<6 -> q cols: each wave's 64 cols = one head (h = 2bj+wc); row-norm via
// 16-lane shfl_xor reduce over nj-frags; writes qn bf16 [bh][n][64] direct.
// bj>=6 -> v cols, written TRANSPOSED as vbfT [bh][d][m] bf16.
// =======================================================================
__global__ __launch_bounds__(256)
void gemm_qkv_mfma(const u16* __restrict__ xbf, const u16* __restrict__ wqv,
                   u16* __restrict__ qnbf, u16* __restrict__ vbfT)
{
    __shared__ u16 As[128*64];
    __shared__ u16 Bs[128*64];
    const int m0 = blockIdx.x * 128;
    const int bj = blockIdx.y;
    const int tid = threadIdx.x;
    f32x4 acc[4][4];
    #pragma unroll
    for (int i = 0; i < 4; ++i)
        #pragma unroll
        for (int j = 0; j < 4; ++j) acc[i][j] = (f32x4){0.f,0.f,0.f,0.f};

    mfma_gemm_core((const char*)xbf + (size_t)m0*1536,
                   (const char*)wqv + (size_t)bj*128*1536,
                   As, Bs, tid, acc);

    const int l = tid & 63, w = tid >> 6;
    const int wr = w >> 1, wc = w & 1;
    const int rbase = m0 + wr*64 + ((l >> 4) << 2);
    if (bj < 6) {
        const int h = 2*bj + wc;                   // wave's 64 cols = head h
        #pragma unroll
        for (int mi = 0; mi < 4; ++mi)
            #pragma unroll
            for (int rr = 0; rr < 4; ++rr) {
                float s =      acc[mi][0][rr]*acc[mi][0][rr];
                s = fmaf(acc[mi][1][rr], acc[mi][1][rr], s);
                s = fmaf(acc[mi][2][rr], acc[mi][2][rr], s);
                s = fmaf(acc[mi][3][rr], acc[mi][3][rr], s);
                #pragma unroll
                for (int off = 1; off < 16; off <<= 1) s += __shfl_xor(s, off);
                const float inv = 1.0f / (sqrtf(s) + 1e-8f);
                const int m = rbase + mi*16 + rr;
                const int b_ = m >> 8, n_ = m & 255;
                u16* row = qnbf + ((((size_t)b_*12 + h) << 8) + n_)*64;
                #pragma unroll
                for (int nj = 0; nj < 4; ++nj)
                    row[nj*16 + (l & 15)] = f2bf(acc[mi][nj][rr] * inv);
            }
    } else {
        const int colb = (bj - 6)*128 + wc*64;
        #pragma unroll
        for (int mi = 0; mi < 4; ++mi)
            #pragma unroll
            for (int nj = 0; nj < 4; ++nj) {
                const int col = colb + nj*16 + (l & 15);
                const int h = col >> 6, d = col & 63;
                const int m = rbase + mi*16;        // rows m..m+3 (consecutive)
                const int b_ = m >> 8, n_ = m & 255;
                uint2 o = make_uint2(pack2bf(acc[mi][nj][0], acc[mi][nj][1]),
                                     pack2bf(acc[mi][nj][2], acc[mi][nj][3]));
                *(uint2*)&vbfT[(((size_t)b_*12 + h)*64 + d)*256 + n_] = o;
            }
    }
}

// =======================================================================
// K5: out = ctx @ w_proj^T + b_proj. ctxb [16384][768] bf16, wpb [768][768] bf16.
// =======================================================================
__global__ __launch_bounds__(256)
void gemm_proj_mfma(const u16* __restrict__ ctxb, const u16* __restrict__ wpb,
                    const float* __restrict__ bias, float* __restrict__ out)
{
    __shared__ u16 As[128*64];
    __shared__ u16 Bs[128*64];
    const int m0 = blockIdx.x * 128;
    const int n0 = blockIdx.y * 128;
    const int tid = threadIdx.x;
    f32x4 acc[4][4];
    #pragma unroll
    for (int i = 0; i < 4; ++i)
        #pragma unroll
        for (int j = 0; j < 4; ++j) acc[i][j] = (f32x4){0.f,0.f,0.f,0.f};

    mfma_gemm_core((const char*)ctxb + (size_t)m0*1536,
                   (const char*)wpb + (size_t)n0*1536,
                   As, Bs, tid, acc);

    const int l = tid & 63, w = tid >> 6;
    const int wr = w >> 1, wc = w & 1;
    const int rbase = m0 + wr*64 + ((l >> 4) << 2);
    #pragma unroll
    for (int mi = 0; mi < 4; ++mi)
        #pragma unroll
        for (int nj = 0; nj < 4; ++nj) {
            const int col = n0 + wc*64 + nj*16 + (l & 15);
            const float bv = bias[col];
            #pragma unroll
            for (int rr = 0; rr < 4; ++rr) {
                const int m = rbase + mi*16 + rr;
                out[(size_t)m*768 + col] = acc[mi][nj][rr] + bv;
            }
        }
}

// =======================================================================
// K2: K[n][m] = exp(10*cos(n,m) - 10) off-diag, 0 on diag. bf16 out.
// MFMA on qn bf16 tiles, XOR-swizzled LDS, fused exp epilogue.
// =======================================================================
__global__ __launch_bounds__(256)
void cost_kernel(const u16* __restrict__ qnbf, u16* __restrict__ Kmat)
{
    __shared__ u16 Qa[128*64];     // [row][64 k] bf16, slot s holds global slot s^(row&7)
    __shared__ u16 Qb[128*64];
    const int bh = blockIdx.y;
    const int tr = (blockIdx.x >> 1) * 128;
    const int tc = (blockIdx.x & 1) * 128;
    const char* qb = (const char*)(qnbf + (size_t)bh * 16384);
    const int tid = threadIdx.x;
    const int l = tid & 63, w = tid >> 6;
    const int wr = w >> 1, wc = w & 1;

    // ---- stage both tiles: 4 issues/wave/array; rows 8*(i*4+w)+(l>>3)
    {
        const int co = ((l & 7) ^ (l >> 3)) << 4;   // inverse-swizzled source slot
        const int rl = l >> 3;
        #pragma unroll
        for (int i = 0; i < 4; ++i) {
            const int ch = i*4 + w;                 // chunk 0..15
            gload_lds16(qb + (size_t)(tr + ch*8 + rl)*128 + co, (char*)Qa + ch*1024);
            gload_lds16(qb + (size_t)(tc + ch*8 + rl)*128 + co, (char*)Qb + ch*1024);
        }
    }
    __syncthreads();

    f32x4 acc[4][4];
    #pragma unroll
    for (int i = 0; i < 4; ++i)
        #pragma unroll
        for (int j = 0; j < 4; ++j) acc[i][j] = (f32x4){0.f,0.f,0.f,0.f};

    bf16x8 af[2][4], bfr[2][4];
    #pragma unroll
    for (int kk = 0; kk < 2; ++kk) {
        const int kb = kk*64 + ((l >> 4) << 4);
        #pragma unroll
        for (int f = 0; f < 4; ++f) {
            const int ra = wr*64 + f*16 + (l & 15);
            af[kk][f]  = *(const bf16x8*)((char*)Qa + ra*128 + (kb ^ ((ra & 7) << 4)));
            const int rb = wc*64 + f*16 + (l & 15);
            bfr[kk][f] = *(const bf16x8*)((char*)Qb + rb*128 + (kb ^ ((rb & 7) << 4)));
        }
    }
    #pragma unroll
    for (int mi = 0; mi < 4; ++mi)
        #pragma unroll
        for (int nj = 0; nj < 4; ++nj) {
            acc[mi][nj] = __builtin_amdgcn_mfma_f32_16x16x32_bf16(
                              af[0][mi], bfr[0][nj], acc[mi][nj], 0, 0, 0);
            acc[mi][nj] = __builtin_amdgcn_mfma_f32_16x16x32_bf16(
                              af[1][mi], bfr[1][nj], acc[mi][nj], 0, 0, 0);
        }

    // ---- epilogue: exp(10*s - 10), diag -> 0, bf16 store
    u16* Kb = Kmat + (size_t)bh * 65536;
    #pragma unroll
    for (int mi = 0; mi < 4; ++mi)
        #pragma unroll
        for (int nj = 0; nj < 4; ++nj) {
            const int gr0 = tr + wr*64 + mi*16 + ((l >> 4) << 2);
            const int gc  = tc + wc*64 + nj*16 + (l & 15);
            #pragma unroll
            for (int rr = 0; rr < 4; ++rr) {
                const int gr = gr0 + rr;
                const float s = acc[mi][nj][rr];
                const float km = (gr == gc) ? 0.f : __expf(fmaf(10.f, s, -10.f));
                Kb[(size_t)gr * 256 + gc] = f2bf(km);
            }
        }
}

// =======================================================================
// K3+K4 FUSED (v3, 1-barrier iterations): Sinkhorn + softmax + PV, 512 thr.
// Key layout fact: matvec B-operand = x broadcast to all 16 cols, so D is
// column-redundant -> EVERY lane holds y for its wave's 8 rows
// (rows rowb+(l>>4)*4+j and +16). Owner-computes update: each lane computes
// xn = (1/256)*rcp(y) locally; (l&15)==0 lanes publish bf16 x to LDS (rows
// unique per wave); ONE __syncthreads per iteration. usave/xv fp32 published
// only at it==18/19. MFMA chains split 4-deep for ILP.
// Phase 3+4 as v2: P-frag built elementwise from kf, consumed immediately.
// =======================================================================
__global__ __launch_bounds__(512, 2)
void sinkhorn_attn_kernel(const u16* __restrict__ Kmat, const u16* __restrict__ vbfT,
                          u16* __restrict__ ctxc)
{
    __shared__ u16 Vt[64*256];       // 32 KB, slot s of row d holds global slot s^(d&7)
    __shared__ __align__(16) float xv[256];
    __shared__ __align__(16) float usave[256];
    __shared__ __align__(16) u16   xbf[256];
    __shared__ float pmax[8];
    const int bh  = blockIdx.x;
    const int b_ = bh / 12, h_ = bh - b_*12;
    const int tid = threadIdx.x;
    const int l = tid & 63, w = tid >> 6;
    const int rowb = w * 32;
    const char* Kg = (const char*)(Kmat + (size_t)bh * 65536);

    // ---- stage Vt (32 KB): 4 issues x (512 thr x 16B); source pre-swizzled
    {
        const char* src = (const char*)(vbfT + (size_t)bh * 16384);
        char* dst = (char*)Vt;
        const int s = l & 31;
        #pragma unroll
        for (int i = 0; i < 4; ++i) {
            const int d = i*16 + w*2 + (l >> 5);
            gload_lds16(src + d*512 + ((s ^ (d & 7)) << 4), dst + i*8192 + w*1024);
        }
    }

    // ---- K frags: lane l holds K[rowb + t*16 + (l&15)][ks*32 + (l>>4)*8 + j]
    bf16x8 kf[2][8];
    {
        const char* kb0 = Kg + (size_t)(rowb + (l & 15)) * 512 + ((l >> 4) << 4);
        #pragma unroll
        for (int t = 0; t < 2; ++t)
            #pragma unroll
            for (int ks = 0; ks < 8; ++ks)
                kf[t][ks] = *(const bf16x8*)(kb0 + t*8192 + ks*64);
    }
    if (tid < 256) xbf[tid] = 0x3f80;    // bf16(1.0)
    __syncthreads();                     // Vt + xbf resident

    // ---- Phase 1: 20 half-iterations, ONE barrier each
    for (int it = 0; it < 20; ++it) {
        f32x4 a0a = {0.f,0.f,0.f,0.f}, a0b = {0.f,0.f,0.f,0.f};
        f32x4 a1a = {0.f,0.f,0.f,0.f}, a1b = {0.f,0.f,0.f,0.f};
        #pragma unroll
        for (int ks = 0; ks < 4; ++ks) {
            const bf16x8 xf = *(const bf16x8*)((const char*)xbf + ks*64 + ((l >> 4) << 4));
            a0a = __builtin_amdgcn_mfma_f32_16x16x32_bf16(kf[0][ks], xf, a0a, 0, 0, 0);
            a1a = __builtin_amdgcn_mfma_f32_16x16x32_bf16(kf[1][ks], xf, a1a, 0, 0, 0);
        }
        #pragma unroll
        for (int ks = 4; ks < 8; ++ks) {
            const bf16x8 xf = *(const bf16x8*)((const char*)xbf + ks*64 + ((l >> 4) << 4));
            a0b = __builtin_amdgcn_mfma_f32_16x16x32_bf16(kf[0][ks], xf, a0b, 0, 0, 0);
            a1b = __builtin_amdgcn_mfma_f32_16x16x32_bf16(kf[1][ks], xf, a1b, 0, 0, 0);
        }
        // every lane holds y for rows r0..r0+3 (t=0) and r0+16..+19 (t=1)
        float xn0[4], xn1[4];
        #pragma unroll
        for (int j = 0; j < 4; ++j) {
            xn0[j] = 0.00390625f * __builtin_amdgcn_rcpf(a0a[j] + a0b[j]);
            xn1[j] = 0.00390625f * __builtin_amdgcn_rcpf(a1a[j] + a1b[j]);
        }
        if ((l & 15) == 0) {
            const int r0 = rowb + ((l >> 4) << 2);
            *(uint2*)&xbf[r0]      = make_uint2(pack2bf(xn0[0], xn0[1]), pack2bf(xn0[2], xn0[3]));
            *(uint2*)&xbf[r0 + 16] = make_uint2(pack2bf(xn1[0], xn1[1]), pack2bf(xn1[2], xn1[3]));
            if (it == 18) {
                *(float4*)&usave[r0]      = make_float4(xn0[0], xn0[1], xn0[2], xn0[3]);
                *(float4*)&usave[r0 + 16] = make_float4(xn1[0], xn1[1], xn1[2], xn1[3]);
            }
            if (it == 19) {
                *(float4*)&xv[r0]      = make_float4(xn0[0], xn0[1], xn0[2], xn0[3]);
                *(float4*)&xv[r0 + 16] = make_float4(xn1[0], xn1[1], xn1[2], xn1[3]);
            }
        }
        __syncthreads();
    }

    // ---- Phase 2: Tmax = max u[n] K[n][m] v[m]
    {
        float mx = 0.f;
        const float u0 = usave[rowb + (l & 15)];
        const float u1 = usave[rowb + 16 + (l & 15)];
        #pragma unroll
        for (int ks = 0; ks < 8; ++ks) {
            const int mbase = ks*32 + ((l >> 4) << 3);
            const float4 va  = *(const float4*)&xv[mbase];
            const float4 vb4 = *(const float4*)&xv[mbase + 4];
            const float vv[8] = {va.x, va.y, va.z, va.w, vb4.x, vb4.y, vb4.z, vb4.w};
            #pragma unroll
            for (int j = 0; j < 8; ++j) {
                mx = fmaxf(mx, u0 * bf2f((u16)kf[0][ks][j]) * vv[j]);
                mx = fmaxf(mx, u1 * bf2f((u16)kf[1][ks][j]) * vv[j]);
            }
        }
        #pragma unroll
        for (int off = 32; off > 0; off >>= 1) mx = fmaxf(mx, __shfl_xor(mx, off));
        if (l == 0) pmax[w] = mx;
    }
    __syncthreads();
    float tm = pmax[0];
    #pragma unroll
    for (int i = 1; i < 8; ++i) tm = fmaxf(tm, pmax[i]);
    const float itmax = 1.0f / tm;

    // ---- Phase 3+4 merged: per t-half: P frag -> immediate PV MFMA
    u16* outp = ctxc + ((size_t)b_*256)*768 + h_*64;
    #pragma unroll
    for (int t = 0; t < 2; ++t) {
        const int rown = rowb + t*16 + (l & 15);
        const float an = usave[rown] * itmax * 0.125f;
        float psum = 0.f;
        f32x4 acc0 = {0.f,0.f,0.f,0.f}, acc1 = {0.f,0.f,0.f,0.f};
        f32x4 acc2 = {0.f,0.f,0.f,0.f}, acc3 = {0.f,0.f,0.f,0.f};
        #pragma unroll
        for (int ks = 0; ks < 8; ++ks) {
            const int mbase = ks*32 + ((l >> 4) << 3);
            const float4 va  = *(const float4*)&xv[mbase];
            const float4 vb4 = *(const float4*)&xv[mbase + 4];
            const float vv[8] = {va.x, va.y, va.z, va.w, vb4.x, vb4.y, vb4.z, vb4.w};
            float p[8];
            #pragma unroll
            for (int j = 0; j < 8; ++j)
                p[j] = __expf(an * bf2f((u16)kf[t][ks][j]) * vv[j]);
            const int dj = rown - mbase;
            if (dj >= 0 && dj < 8) p[dj] = 1.13314845f;     // exp(0.125)
            psum += ((p[0]+p[1]) + (p[2]+p[3])) + ((p[4]+p[5]) + (p[6]+p[7]));
            bf16x8 pf;
            #pragma unroll
            for (int j = 0; j < 8; ++j) pf[j] = (short)f2bf(p[j]);
            const int bc = ks*64 + ((l >> 4) << 4);
            {
                const int d = (l & 15);
                const bf16x8 vf = *(const bf16x8*)((char*)Vt + d*512 + (bc ^ ((d & 7) << 4)));
                acc0 = __builtin_amdgcn_mfma_f32_16x16x32_bf16(vf, pf, acc0, 0, 0, 0);
            }
            {
                const int d = 16 + (l & 15);
                const bf16x8 vf = *(const bf16x8*)((char*)Vt + d*512 + (bc ^ ((d & 7) << 4)));
                acc1 = __builtin_amdgcn_mfma_f32_16x16x32_bf16(vf, pf, acc1, 0, 0, 0);
            }
            {
                const int d = 32 + (l & 15);
                const bf16x8 vf = *(const bf16x8*)((char*)Vt + d*512 + (bc ^ ((d & 7) << 4)));
                acc2 = __builtin_amdgcn_mfma_f32_16x16x32_bf16(vf, pf, acc2, 0, 0, 0);
            }
            {
                const int d = 48 + (l & 15);
                const bf16x8 vf = *(const bf16x8*)((char*)Vt + d*512 + (bc ^ ((d & 7) << 4)));
                acc3 = __builtin_amdgcn_mfma_f32_16x16x32_bf16(vf, pf, acc3, 0, 0, 0);
            }
        }
        psum += __shfl_xor(psum, 16);
        psum += __shfl_xor(psum, 32);                  // 4 lanes/row summed
        const float is = 1.0f / psum;
        const int d0 = (l >> 4) << 2;
        uint2 o0 = make_uint2(pack2bf(acc0[0]*is, acc0[1]*is), pack2bf(acc0[2]*is, acc0[3]*is));
        uint2 o1 = make_uint2(pack2bf(acc1[0]*is, acc1[1]*is), pack2bf(acc1[2]*is, acc1[3]*is));
        uint2 o2 = make_uint2(pack2bf(acc2[0]*is, acc2[1]*is), pack2bf(acc2[2]*is, acc2[3]*is));
        uint2 o3 = make_uint2(pack2bf(acc3[0]*is, acc3[1]*is), pack2bf(acc3[2]*is, acc3[3]*is));
        u16* orow = outp + (size_t)rown*768;
        *(uint2*)&orow[d0]      = o0;
        *(uint2*)&orow[16 + d0] = o1;
        *(uint2*)&orow[32 + d0] = o2;
        *(uint2*)&orow[48 + d0] = o3;
    }
}

// =======================================================================
extern "C" void kernel_launch(void* const* d_in, const int* in_sizes, int n_in,
                              void* d_out, int out_size, void* d_ws, size_t ws_size,
                              hipStream_t stream)
{
    (void)in_sizes; (void)n_in; (void)out_size; (void)ws_size;
    const float* x      = (const float*)d_in[0];
    const float* w_qkv  = (const float*)d_in[1];
    const float* w_proj = (const float*)d_in[2];
    const float* b_proj = (const float*)d_in[3];
    float* out = (float*)d_out;

    char* w = (char*)d_ws;
    // workspace layout (bytes):
    u16*   xbf  = (u16*)  (w);                     //  25,165,824  x bf16 [16384][768]
    u16*   wqv  = (u16*)  (w + 25165824);          //   2,359,296  w q+v rows bf16 [1536][768]
    u16*   wpb  = (u16*)  (w + 27525120);          //   1,179,648  w_proj bf16 [768][768]
    u16*   qnbf = (u16*)  (w + 28704768);          //  25,165,824  qn bf16 [768][256][64]
    u16*   vbfT = (u16*)  (w + 79036416);          //  25,165,824  v^T bf16 [768][64][256]
    u16*   ctxc = (u16*)  (w + 104202240);         //  25,165,824  ctx bf16 [64][256][768]
    u16*   Km   = (u16*)  (w + 130944000);         // 100,663,296  K bf16 [768][256][256]
    // total ~231.6 MB

    conv_bf16           <<<dim3(6144),    256, 0, stream>>>(x, xbf, 1572864);
    conv_wqv            <<<dim3(576),     256, 0, stream>>>(w_qkv, wqv);
    conv_bf16           <<<dim3(288),     256, 0, stream>>>(w_proj, wpb, 73728);
    gemm_qkv_mfma       <<<dim3(128, 12), 256, 0, stream>>>(xbf, wqv, qnbf, vbfT);
    cost_kernel         <<<dim3(4, 768),  256, 0, stream>>>(qnbf, Km);
    sinkhorn_attn_kernel<<<dim3(768),     512, 0, stream>>>(Km, vbfT, ctxc);
    gemm_proj_mfma      <<<dim3(128, 6),  256, 0, stream>>>(ctxc, wpb, b_proj, out);
}

// Round 11
// 222.399 us; speedup vs baseline: 1.1803x; 1.0192x over previous
//
#include <hip/hip_runtime.h>

typedef unsigned short u16;
typedef unsigned int   u32;
typedef __attribute__((ext_vector_type(8))) short bf16x8;
typedef __attribute__((ext_vector_type(4))) float f32x4;

// ---------- bf16 helpers (manual, RNE) ----------
__device__ __forceinline__ u16 f2bf(float f) {
    u32 u = __float_as_uint(f);
    u += 0x7fffu + ((u >> 16) & 1u);
    return (u16)(u >> 16);
}
__device__ __forceinline__ float bf2f(u16 s) {
    return __uint_as_float(((u32)s) << 16);
}
__device__ __forceinline__ u32 pack2bf(float f0, float f1) {
    return (u32)f2bf(f0) | ((u32)f2bf(f1) << 16);
}
// HW packed conversion: d = {lo: bf16(f0), hi: bf16(f1)} in ONE VALU op
__device__ __forceinline__ u32 cvtpk2bf(float f0, float f1) {
    u32 r;
    asm("v_cvt_pk_bf16_f32 %0, %1, %2" : "=v"(r) : "v"(f0), "v"(f1));
    return r;
}

__device__ __forceinline__ void gload_lds16(const void* g, void* l) {
    __builtin_amdgcn_global_load_lds(
        (const __attribute__((address_space(1))) u32*)g,
        (__attribute__((address_space(3))) u32*)l, 16, 0, 0);
}

// =======================================================================
// fp32 -> bf16 converters
// =======================================================================
__global__ __launch_bounds__(256)
void conv_bf16(const float* __restrict__ src, u16* __restrict__ dst, int n8)
{
    const int i = blockIdx.x * 256 + threadIdx.x;   // 8 elements per thread
    if (i < n8) {
        const float4 a = ((const float4*)src)[2*i];
        const float4 b = ((const float4*)src)[2*i + 1];
        ((uint4*)dst)[i] = make_uint4(pack2bf(a.x,a.y), pack2bf(a.z,a.w),
                                      pack2bf(b.x,b.y), pack2bf(b.z,b.w));
    }
}

// w_qkv [2304][768]: keep q rows 0..767 and v rows 1536..2303 -> wqv [1536][768]
__global__ __launch_bounds__(256)
void conv_wqv(const float* __restrict__ w, u16* __restrict__ dst)
{
    const int i = blockIdx.x * 256 + threadIdx.x;   // chunk of 8, 96 chunks/row
    const int row = i / 96;
    const int cc  = (i - row * 96) * 8;
    const int srow = row + (row >= 768 ? 768 : 0);
    const float4 a = *(const float4*)&w[(size_t)srow*768 + cc];
    const float4 b = *(const float4*)&w[(size_t)srow*768 + cc + 4];
    *(uint4*)&dst[(size_t)row*768 + cc] =
        make_uint4(pack2bf(a.x,a.y), pack2bf(a.z,a.w), pack2bf(b.x,b.y), pack2bf(b.z,b.w));
}

// =======================================================================
// Shared MFMA GEMM core: C[128x128] tile, K=768, bf16 A[.,768] x B[.,768]^T.
// BK=64, 4 waves (2x2), 16x16x32 MFMA, global_load_lds + XOR-swizzled LDS.
// =======================================================================
__device__ __forceinline__ void mfma_gemm_core(
    const char* __restrict__ Arow0,   // &A[m0][0] as bytes (row stride 1536)
    const char* __restrict__ Brow0,   // &B[n0][0] as bytes
    u16* As, u16* Bs, const int tid, f32x4 acc[4][4])
{
    const int l  = tid & 63, w = tid >> 6;
    const int wr = w >> 1,  wc = w & 1;
    char* Asb = (char*)As;
    char* Bsb = (char*)Bs;
    const int co = 16 * ((l & 7) ^ (l >> 3));       // swizzled global byte col
    const size_t rstep = (size_t)(l >> 3) * 1536;
    const int rsw = (l & 7) << 4;                   // read-side XOR

    for (int k0 = 0; k0 < 1536; k0 += 128) {        // 12 K-steps of 64 bf16
        #pragma unroll
        for (int i = 0; i < 4; ++i) {
            const int rb = i*32 + w*8;
            gload_lds16(Arow0 + (size_t)rb*1536 + rstep + k0 + co, Asb + i*4096 + w*1024);
            gload_lds16(Brow0 + (size_t)rb*1536 + rstep + k0 + co, Bsb + i*4096 + w*1024);
        }
        __syncthreads();
        bf16x8 af[2][4], bfr[2][4];
        #pragma unroll
        for (int kk = 0; kk < 2; ++kk) {
            const int coff = (kk*64 + ((l >> 4) << 4)) ^ rsw;
            #pragma unroll
            for (int mi = 0; mi < 4; ++mi) {
                const int rowA = wr*64 + mi*16 + (l & 15);
                af[kk][mi]  = *(const bf16x8*)(Asb + rowA*128 + coff);
                const int rowB = wc*64 + mi*16 + (l & 15);
                bfr[kk][mi] = *(const bf16x8*)(Bsb + rowB*128 + coff);
            }
        }
        #pragma unroll
        for (int mi = 0; mi < 4; ++mi)
            #pragma unroll
            for (int nj = 0; nj < 4; ++nj) {
                acc[mi][nj] = __builtin_amdgcn_mfma_f32_16x16x32_bf16(
                                  af[0][mi], bfr[0][nj], acc[mi][nj], 0, 0, 0);
                acc[mi][nj] = __builtin_amdgcn_mfma_f32_16x16x32_bf16(
                                  af[1][mi], bfr[1][nj], acc[mi][nj], 0, 0, 0);
            }
        __syncthreads();
    }
}

// =======================================================================
// K0: q/v projection + FUSED q-normalize. xbf [16384][768], wqv [1536][768].
// bj<6 -> q cols: each wave's 64 cols = one head (h = 2bj+wc); row-norm via
// 16-lane shfl_xor reduce over nj-frags; writes qn bf16 [bh][n][64] direct.
// bj>=6 -> v cols, written TRANSPOSED as vbfT [bh][d][m] bf16.
// =======================================================================
__global__ __launch_bounds__(256)
void gemm_qkv_mfma(const u16* __restrict__ xbf, const u16* __restrict__ wqv,
                   u16* __restrict__ qnbf, u16* __restrict__ vbfT)
{
    __shared__ u16 As[128*64];
    __shared__ u16 Bs[128*64];
    const int m0 = blockIdx.x * 128;
    const int bj = blockIdx.y;
    const int tid = threadIdx.x;
    f32x4 acc[4][4];
    #pragma unroll
    for (int i = 0; i < 4; ++i)
        #pragma unroll
        for (int j = 0; j < 4; ++j) acc[i][j] = (f32x4){0.f,0.f,0.f,0.f};

    mfma_gemm_core((const char*)xbf + (size_t)m0*1536,
                   (const char*)wqv + (size_t)bj*128*1536,
                   As, Bs, tid, acc);

    const int l = tid & 63, w = tid >> 6;
    const int wr = w >> 1, wc = w & 1;
    const int rbase = m0 + wr*64 + ((l >> 4) << 2);
    if (bj < 6) {
        const int h = 2*bj + wc;                   // wave's 64 cols = head h
        #pragma unroll
        for (int mi = 0; mi < 4; ++mi)
            #pragma unroll
            for (int rr = 0; rr < 4; ++rr) {
                float s =      acc[mi][0][rr]*acc[mi][0][rr];
                s = fmaf(acc[mi][1][rr], acc[mi][1][rr], s);
                s = fmaf(acc[mi][2][rr], acc[mi][2][rr], s);
                s = fmaf(acc[mi][3][rr], acc[mi][3][rr], s);
                #pragma unroll
                for (int off = 1; off < 16; off <<= 1) s += __shfl_xor(s, off);
                const float inv = 1.0f / (sqrtf(s) + 1e-8f);
                const int m = rbase + mi*16 + rr;
                const int b_ = m >> 8, n_ = m & 255;
                u16* row = qnbf + ((((size_t)b_*12 + h) << 8) + n_)*64;
                #pragma unroll
                for (int nj = 0; nj < 4; ++nj)
                    row[nj*16 + (l & 15)] = f2bf(acc[mi][nj][rr] * inv);
            }
    } else {
        const int colb = (bj - 6)*128 + wc*64;
        #pragma unroll
        for (int mi = 0; mi < 4; ++mi)
            #pragma unroll
            for (int nj = 0; nj < 4; ++nj) {
                const int col = colb + nj*16 + (l & 15);
                const int h = col >> 6, d = col & 63;
                const int m = rbase + mi*16;        // rows m..m+3 (consecutive)
                const int b_ = m >> 8, n_ = m & 255;
                uint2 o = make_uint2(pack2bf(acc[mi][nj][0], acc[mi][nj][1]),
                                     pack2bf(acc[mi][nj][2], acc[mi][nj][3]));
                *(uint2*)&vbfT[(((size_t)b_*12 + h)*64 + d)*256 + n_] = o;
            }
    }
}

// =======================================================================
// K5: out = ctx @ w_proj^T + b_proj. ctxb [16384][768] bf16, wpb [768][768] bf16.
// =======================================================================
__global__ __launch_bounds__(256)
void gemm_proj_mfma(const u16* __restrict__ ctxb, const u16* __restrict__ wpb,
                    const float* __restrict__ bias, float* __restrict__ out)
{
    __shared__ u16 As[128*64];
    __shared__ u16 Bs[128*64];
    const int m0 = blockIdx.x * 128;
    const int n0 = blockIdx.y * 128;
    const int tid = threadIdx.x;
    f32x4 acc[4][4];
    #pragma unroll
    for (int i = 0; i < 4; ++i)
        #pragma unroll
        for (int j = 0; j < 4; ++j) acc[i][j] = (f32x4){0.f,0.f,0.f,0.f};

    mfma_gemm_core((const char*)ctxb + (size_t)m0*1536,
                   (const char*)wpb + (size_t)n0*1536,
                   As, Bs, tid, acc);

    const int l = tid & 63, w = tid >> 6;
    const int wr = w >> 1, wc = w & 1;
    const int rbase = m0 + wr*64 + ((l >> 4) << 2);
    #pragma unroll
    for (int mi = 0; mi < 4; ++mi)
        #pragma unroll
        for (int nj = 0; nj < 4; ++nj) {
            const int col = n0 + wc*64 + nj*16 + (l & 15);
            const float bv = bias[col];
            #pragma unroll
            for (int rr = 0; rr < 4; ++rr) {
                const int m = rbase + mi*16 + rr;
                out[(size_t)m*768 + col] = acc[mi][nj][rr] + bv;
            }
        }
}

// =======================================================================
// K2: K[n][m] = exp(10*cos(n,m) - 10) off-diag, 0 on diag. bf16 out.
// MFMA on qn bf16 tiles, XOR-swizzled LDS, fused exp epilogue.
// =======================================================================
__global__ __launch_bounds__(256)
void cost_kernel(const u16* __restrict__ qnbf, u16* __restrict__ Kmat)
{
    __shared__ u16 Qa[128*64];     // [row][64 k] bf16, slot s holds global slot s^(row&7)
    __shared__ u16 Qb[128*64];
    const int bh = blockIdx.y;
    const int tr = (blockIdx.x >> 1) * 128;
    const int tc = (blockIdx.x & 1) * 128;
    const char* qb = (const char*)(qnbf + (size_t)bh * 16384);
    const int tid = threadIdx.x;
    const int l = tid & 63, w = tid >> 6;
    const int wr = w >> 1, wc = w & 1;

    // ---- stage both tiles: 4 issues/wave/array; rows 8*(i*4+w)+(l>>3)
    {
        const int co = ((l & 7) ^ (l >> 3)) << 4;   // inverse-swizzled source slot
        const int rl = l >> 3;
        #pragma unroll
        for (int i = 0; i < 4; ++i) {
            const int ch = i*4 + w;                 // chunk 0..15
            gload_lds16(qb + (size_t)(tr + ch*8 + rl)*128 + co, (char*)Qa + ch*1024);
            gload_lds16(qb + (size_t)(tc + ch*8 + rl)*128 + co, (char*)Qb + ch*1024);
        }
    }
    __syncthreads();

    f32x4 acc[4][4];
    #pragma unroll
    for (int i = 0; i < 4; ++i)
        #pragma unroll
        for (int j = 0; j < 4; ++j) acc[i][j] = (f32x4){0.f,0.f,0.f,0.f};

    bf16x8 af[2][4], bfr[2][4];
    #pragma unroll
    for (int kk = 0; kk < 2; ++kk) {
        const int kb = kk*64 + ((l >> 4) << 4);
        #pragma unroll
        for (int f = 0; f < 4; ++f) {
            const int ra = wr*64 + f*16 + (l & 15);
            af[kk][f]  = *(const bf16x8*)((char*)Qa + ra*128 + (kb ^ ((ra & 7) << 4)));
            const int rb = wc*64 + f*16 + (l & 15);
            bfr[kk][f] = *(const bf16x8*)((char*)Qb + rb*128 + (kb ^ ((rb & 7) << 4)));
        }
    }
    #pragma unroll
    for (int mi = 0; mi < 4; ++mi)
        #pragma unroll
        for (int nj = 0; nj < 4; ++nj) {
            acc[mi][nj] = __builtin_amdgcn_mfma_f32_16x16x32_bf16(
                              af[0][mi], bfr[0][nj], acc[mi][nj], 0, 0, 0);
            acc[mi][nj] = __builtin_amdgcn_mfma_f32_16x16x32_bf16(
                              af[1][mi], bfr[1][nj], acc[mi][nj], 0, 0, 0);
        }

    // ---- epilogue: exp(10*s - 10), diag -> 0, bf16 store
    u16* Kb = Kmat + (size_t)bh * 65536;
    #pragma unroll
    for (int mi = 0; mi < 4; ++mi)
        #pragma unroll
        for (int nj = 0; nj < 4; ++nj) {
            const int gr0 = tr + wr*64 + mi*16 + ((l >> 4) << 2);
            const int gc  = tc + wc*64 + nj*16 + (l & 15);
            #pragma unroll
            for (int rr = 0; rr < 4; ++rr) {
                const int gr = gr0 + rr;
                const float s = acc[mi][nj][rr];
                const float km = (gr == gc) ? 0.f : __expf(fmaf(10.f, s, -10.f));
                Kb[(size_t)gr * 256 + gc] = f2bf(km);
            }
        }
}

// =======================================================================
// K3+K4 FUSED (v4, VALU-slimmed): Sinkhorn + softmax + PV, 512 thr/(b,h).
// v3 structure kept (1-barrier iters, owner-computes update). New in v4:
//  - all hot bf16 packing via v_cvt_pk_bf16_f32 (1 op per pair) instead of
//    manual RNE f2bf + 16-bit inserts (~8 ops per element);
//  - phase 2 factors u out of the row max: max(u*k*v) = u*max(k*v) (exact,
//    all of kf[t]'s elements belong to one row);
//  - epilogue + phase-1 x-publish also cvt_pk.
// =======================================================================
__global__ __launch_bounds__(512, 2)
void sinkhorn_attn_kernel(const u16* __restrict__ Kmat, const u16* __restrict__ vbfT,
                          u16* __restrict__ ctxc)
{
    __shared__ u16 Vt[64*256];       // 32 KB, slot s of row d holds global slot s^(d&7)
    __shared__ __align__(16) float xv[256];
    __shared__ __align__(16) float usave[256];
    __shared__ __align__(16) u16   xbf[256];
    __shared__ float pmax[8];
    const int bh  = blockIdx.x;
    const int b_ = bh / 12, h_ = bh - b_*12;
    const int tid = threadIdx.x;
    const int l = tid & 63, w = tid >> 6;
    const int rowb = w * 32;
    const char* Kg = (const char*)(Kmat + (size_t)bh * 65536);

    // ---- stage Vt (32 KB): 4 issues x (512 thr x 16B); source pre-swizzled
    {
        const char* src = (const char*)(vbfT + (size_t)bh * 16384);
        char* dst = (char*)Vt;
        const int s = l & 31;
        #pragma unroll
        for (int i = 0; i < 4; ++i) {
            const int d = i*16 + w*2 + (l >> 5);
            gload_lds16(src + d*512 + ((s ^ (d & 7)) << 4), dst + i*8192 + w*1024);
        }
    }

    // ---- K frags: lane l holds K[rowb + t*16 + (l&15)][ks*32 + (l>>4)*8 + j]
    bf16x8 kf[2][8];
    {
        const char* kb0 = Kg + (size_t)(rowb + (l & 15)) * 512 + ((l >> 4) << 4);
        #pragma unroll
        for (int t = 0; t < 2; ++t)
            #pragma unroll
            for (int ks = 0; ks < 8; ++ks)
                kf[t][ks] = *(const bf16x8*)(kb0 + t*8192 + ks*64);
    }
    if (tid < 256) xbf[tid] = 0x3f80;    // bf16(1.0)
    __syncthreads();                     // Vt + xbf resident

    // ---- Phase 1: 20 half-iterations, ONE barrier each
    for (int it = 0; it < 20; ++it) {
        f32x4 a0a = {0.f,0.f,0.f,0.f}, a0b = {0.f,0.f,0.f,0.f};
        f32x4 a1a = {0.f,0.f,0.f,0.f}, a1b = {0.f,0.f,0.f,0.f};
        #pragma unroll
        for (int ks = 0; ks < 4; ++ks) {
            const bf16x8 xf = *(const bf16x8*)((const char*)xbf + ks*64 + ((l >> 4) << 4));
            a0a = __builtin_amdgcn_mfma_f32_16x16x32_bf16(kf[0][ks], xf, a0a, 0, 0, 0);
            a1a = __builtin_amdgcn_mfma_f32_16x16x32_bf16(kf[1][ks], xf, a1a, 0, 0, 0);
        }
        #pragma unroll
        for (int ks = 4; ks < 8; ++ks) {
            const bf16x8 xf = *(const bf16x8*)((const char*)xbf + ks*64 + ((l >> 4) << 4));
            a0b = __builtin_amdgcn_mfma_f32_16x16x32_bf16(kf[0][ks], xf, a0b, 0, 0, 0);
            a1b = __builtin_amdgcn_mfma_f32_16x16x32_bf16(kf[1][ks], xf, a1b, 0, 0, 0);
        }
        // every lane holds y for rows r0..r0+3 (t=0) and r0+16..+19 (t=1)
        float xn0[4], xn1[4];
        #pragma unroll
        for (int j = 0; j < 4; ++j) {
            xn0[j] = 0.00390625f * __builtin_amdgcn_rcpf(a0a[j] + a0b[j]);
            xn1[j] = 0.00390625f * __builtin_amdgcn_rcpf(a1a[j] + a1b[j]);
        }
        const u32 xp0 = cvtpk2bf(xn0[0], xn0[1]);
        const u32 xp1 = cvtpk2bf(xn0[2], xn0[3]);
        const u32 xp2 = cvtpk2bf(xn1[0], xn1[1]);
        const u32 xp3 = cvtpk2bf(xn1[2], xn1[3]);
        if ((l & 15) == 0) {
            const int r0 = rowb + ((l >> 4) << 2);
            *(uint2*)&xbf[r0]      = make_uint2(xp0, xp1);
            *(uint2*)&xbf[r0 + 16] = make_uint2(xp2, xp3);
            if (it == 18) {
                *(float4*)&usave[r0]      = make_float4(xn0[0], xn0[1], xn0[2], xn0[3]);
                *(float4*)&usave[r0 + 16] = make_float4(xn1[0], xn1[1], xn1[2], xn1[3]);
            }
            if (it == 19) {
                *(float4*)&xv[r0]      = make_float4(xn0[0], xn0[1], xn0[2], xn0[3]);
                *(float4*)&xv[r0 + 16] = make_float4(xn1[0], xn1[1], xn1[2], xn1[3]);
            }
        }
        __syncthreads();
    }

    // ---- Phase 2: Tmax = max u[n] K[n][m] v[m] = u[n] * max_m(K*v)
    {
        float mx0 = 0.f, mx1 = 0.f;
        #pragma unroll
        for (int ks = 0; ks < 8; ++ks) {
            const int mbase = ks*32 + ((l >> 4) << 3);
            const float4 va  = *(const float4*)&xv[mbase];
            const float4 vb4 = *(const float4*)&xv[mbase + 4];
            const float vv[8] = {va.x, va.y, va.z, va.w, vb4.x, vb4.y, vb4.z, vb4.w};
            #pragma unroll
            for (int j = 0; j < 8; ++j) {
                mx0 = fmaxf(mx0, bf2f((u16)kf[0][ks][j]) * vv[j]);
                mx1 = fmaxf(mx1, bf2f((u16)kf[1][ks][j]) * vv[j]);
            }
        }
        float mx = fmaxf(usave[rowb + (l & 15)] * mx0,
                         usave[rowb + 16 + (l & 15)] * mx1);
        #pragma unroll
        for (int off = 32; off > 0; off >>= 1) mx = fmaxf(mx, __shfl_xor(mx, off));
        if (l == 0) pmax[w] = mx;
    }
    __syncthreads();
    float tm = pmax[0];
    #pragma unroll
    for (int i = 1; i < 8; ++i) tm = fmaxf(tm, pmax[i]);
    const float itmax = 1.0f / tm;

    // ---- Phase 3+4 merged: per t-half: P frag -> immediate PV MFMA
    u16* outp = ctxc + ((size_t)b_*256)*768 + h_*64;
    #pragma unroll
    for (int t = 0; t < 2; ++t) {
        const int rown = rowb + t*16 + (l & 15);
        const float an = usave[rown] * itmax * 0.125f;
        float psum = 0.f;
        f32x4 acc0 = {0.f,0.f,0.f,0.f}, acc1 = {0.f,0.f,0.f,0.f};
        f32x4 acc2 = {0.f,0.f,0.f,0.f}, acc3 = {0.f,0.f,0.f,0.f};
        #pragma unroll
        for (int ks = 0; ks < 8; ++ks) {
            const int mbase = ks*32 + ((l >> 4) << 3);
            const float4 va  = *(const float4*)&xv[mbase];
            const float4 vb4 = *(const float4*)&xv[mbase + 4];
            const float vv[8] = {va.x, va.y, va.z, va.w, vb4.x, vb4.y, vb4.z, vb4.w};
            float p[8];
            #pragma unroll
            for (int j = 0; j < 8; ++j)
                p[j] = __expf(an * bf2f((u16)kf[t][ks][j]) * vv[j]);
            const int dj = rown - mbase;
            if (dj >= 0 && dj < 8) p[dj] = 1.13314845f;     // exp(0.125)
            psum += ((p[0]+p[1]) + (p[2]+p[3])) + ((p[4]+p[5]) + (p[6]+p[7]));
            uint4 pwv = make_uint4(cvtpk2bf(p[0], p[1]), cvtpk2bf(p[2], p[3]),
                                   cvtpk2bf(p[4], p[5]), cvtpk2bf(p[6], p[7]));
            const bf16x8 pf = *(const bf16x8*)&pwv;
            const int bc = ks*64 + ((l >> 4) << 4);
            {
                const int d = (l & 15);
                const bf16x8 vf = *(const bf16x8*)((char*)Vt + d*512 + (bc ^ ((d & 7) << 4)));
                acc0 = __builtin_amdgcn_mfma_f32_16x16x32_bf16(vf, pf, acc0, 0, 0, 0);
            }
            {
                const int d = 16 + (l & 15);
                const bf16x8 vf = *(const bf16x8*)((char*)Vt + d*512 + (bc ^ ((d & 7) << 4)));
                acc1 = __builtin_amdgcn_mfma_f32_16x16x32_bf16(vf, pf, acc1, 0, 0, 0);
            }
            {
                const int d = 32 + (l & 15);
                const bf16x8 vf = *(const bf16x8*)((char*)Vt + d*512 + (bc ^ ((d & 7) << 4)));
                acc2 = __builtin_amdgcn_mfma_f32_16x16x32_bf16(vf, pf, acc2, 0, 0, 0);
            }
            {
                const int d = 48 + (l & 15);
                const bf16x8 vf = *(const bf16x8*)((char*)Vt + d*512 + (bc ^ ((d & 7) << 4)));
                acc3 = __builtin_amdgcn_mfma_f32_16x16x32_bf16(vf, pf, acc3, 0, 0, 0);
            }
        }
        psum += __shfl_xor(psum, 16);
        psum += __shfl_xor(psum, 32);                  // 4 lanes/row summed
        const float is = 1.0f / psum;
        const int d0 = (l >> 4) << 2;
        uint2 o0 = make_uint2(cvtpk2bf(acc0[0]*is, acc0[1]*is), cvtpk2bf(acc0[2]*is, acc0[3]*is));
        uint2 o1 = make_uint2(cvtpk2bf(acc1[0]*is, acc1[1]*is), cvtpk2bf(acc1[2]*is, acc1[3]*is));
        uint2 o2 = make_uint2(cvtpk2bf(acc2[0]*is, acc2[1]*is), cvtpk2bf(acc2[2]*is, acc2[3]*is));
        uint2 o3 = make_uint2(cvtpk2bf(acc3[0]*is, acc3[1]*is), cvtpk2bf(acc3[2]*is, acc3[3]*is));
        u16* orow = outp + (size_t)rown*768;
        *(uint2*)&orow[d0]      = o0;
        *(uint2*)&orow[16 + d0] = o1;
        *(uint2*)&orow[32 + d0] = o2;
        *(uint2*)&orow[48 + d0] = o3;
    }
}

// =======================================================================
extern "C" void kernel_launch(void* const* d_in, const int* in_sizes, int n_in,
                              void* d_out, int out_size, void* d_ws, size_t ws_size,
                              hipStream_t stream)
{
    (void)in_sizes; (void)n_in; (void)out_size; (void)ws_size;
    const float* x      = (const float*)d_in[0];
    const float* w_qkv  = (const float*)d_in[1];
    const float* w_proj = (const float*)d_in[2];
    const float* b_proj = (const float*)d_in[3];
    float* out = (float*)d_out;

    char* w = (char*)d_ws;
    // workspace layout (bytes):
    u16*   xbf  = (u16*)  (w);                     //  25,165,824  x bf16 [16384][768]
    u16*   wqv  = (u16*)  (w + 25165824);          //   2,359,296  w q+v rows bf16 [1536][768]
    u16*   wpb  = (u16*)  (w + 27525120);          //   1,179,648  w_proj bf16 [768][768]
    u16*   qnbf = (u16*)  (w + 28704768);          //  25,165,824  qn bf16 [768][256][64]
    u16*   vbfT = (u16*)  (w + 79036416);          //  25,165,824  v^T bf16 [768][64][256]
    u16*   ctxc = (u16*)  (w + 104202240);         //  25,165,824  ctx bf16 [64][256][768]
    u16*   Km   = (u16*)  (w + 130944000);         // 100,663,296  K bf16 [768][256][256]
    // total ~231.6 MB

    conv_bf16           <<<dim3(6144),    256, 0, stream>>>(x, xbf, 1572864);
    conv_wqv            <<<dim3(576),     256, 0, stream>>>(w_qkv, wqv);
    conv_bf16           <<<dim3(288),     256, 0, stream>>>(w_proj, wpb, 73728);
    gemm_qkv_mfma       <<<dim3(128, 12), 256, 0, stream>>>(xbf, wqv, qnbf, vbfT);
    cost_kernel         <<<dim3(4, 768),  256, 0, stream>>>(qnbf, Km);
    sinkhorn_attn_kernel<<<dim3(768),     512, 0, stream>>>(Km, vbfT, ctxc);
    gemm_proj_mfma      <<<dim3(128, 6),  256, 0, stream>>>(ctxc, wpb, b_proj, out);
}

// Round 12
// 219.617 us; speedup vs baseline: 1.1952x; 1.0127x over previous
//
#include <hip/hip_runtime.h>

typedef unsigned short u16;
typedef unsigned int   u32;
typedef __attribute__((ext_vector_type(8))) short bf16x8;
typedef __attribute__((ext_vector_type(4))) float f32x4;

// ---------- bf16 helpers (manual, RNE) ----------
__device__ __forceinline__ u16 f2bf(float f) {
    u32 u = __float_as_uint(f);
    u += 0x7fffu + ((u >> 16) & 1u);
    return (u16)(u >> 16);
}
__device__ __forceinline__ float bf2f(u16 s) {
    return __uint_as_float(((u32)s) << 16);
}
__device__ __forceinline__ u32 pack2bf(float f0, float f1) {
    return (u32)f2bf(f0) | ((u32)f2bf(f1) << 16);
}
// HW packed conversion: d = {lo: bf16(f0), hi: bf16(f1)} in ONE VALU op
__device__ __forceinline__ u32 cvtpk2bf(float f0, float f1) {
    u32 r;
    asm("v_cvt_pk_bf16_f32 %0, %1, %2" : "=v"(r) : "v"(f0), "v"(f1));
    return r;
}

__device__ __forceinline__ void gload_lds16(const void* g, void* l) {
    __builtin_amdgcn_global_load_lds(
        (const __attribute__((address_space(1))) u32*)g,
        (__attribute__((address_space(3))) u32*)l, 16, 0, 0);
}

// =======================================================================
// fp32 -> bf16 converters
// =======================================================================
__global__ __launch_bounds__(256)
void conv_bf16(const float* __restrict__ src, u16* __restrict__ dst, int n8)
{
    const int i = blockIdx.x * 256 + threadIdx.x;   // 8 elements per thread
    if (i < n8) {
        const float4 a = ((const float4*)src)[2*i];
        const float4 b = ((const float4*)src)[2*i + 1];
        ((uint4*)dst)[i] = make_uint4(pack2bf(a.x,a.y), pack2bf(a.z,a.w),
                                      pack2bf(b.x,b.y), pack2bf(b.z,b.w));
    }
}

// w_qkv [2304][768]: keep q rows 0..767 and v rows 1536..2303 -> wqv [1536][768]
__global__ __launch_bounds__(256)
void conv_wqv(const float* __restrict__ w, u16* __restrict__ dst)
{
    const int i = blockIdx.x * 256 + threadIdx.x;   // chunk of 8, 96 chunks/row
    const int row = i / 96;
    const int cc  = (i - row * 96) * 8;
    const int srow = row + (row >= 768 ? 768 : 0);
    const float4 a = *(const float4*)&w[(size_t)srow*768 + cc];
    const float4 b = *(const float4*)&w[(size_t)srow*768 + cc + 4];
    *(uint4*)&dst[(size_t)row*768 + cc] =
        make_uint4(pack2bf(a.x,a.y), pack2bf(a.z,a.w), pack2bf(b.x,b.y), pack2bf(b.z,b.w));
}

// =======================================================================
// Shared MFMA GEMM core: C[128x128] tile, K=768, bf16 A[.,768] x B[.,768]^T.
// BK=64, 4 waves (2x2), 16x16x32 MFMA, global_load_lds + XOR-swizzled LDS.
// =======================================================================
__device__ __forceinline__ void mfma_gemm_core(
    const char* __restrict__ Arow0,   // &A[m0][0] as bytes (row stride 1536)
    const char* __restrict__ Brow0,   // &B[n0][0] as bytes
    u16* As, u16* Bs, const int tid, f32x4 acc[4][4])
{
    const int l  = tid & 63, w = tid >> 6;
    const int wr = w >> 1,  wc = w & 1;
    char* Asb = (char*)As;
    char* Bsb = (char*)Bs;
    const int co = 16 * ((l & 7) ^ (l >> 3));       // swizzled global byte col
    const size_t rstep = (size_t)(l >> 3) * 1536;
    const int rsw = (l & 7) << 4;                   // read-side XOR

    for (int k0 = 0; k0 < 1536; k0 += 128) {        // 12 K-steps of 64 bf16
        #pragma unroll
        for (int i = 0; i < 4; ++i) {
            const int rb = i*32 + w*8;
            gload_lds16(Arow0 + (size_t)rb*1536 + rstep + k0 + co, Asb + i*4096 + w*1024);
            gload_lds16(Brow0 + (size_t)rb*1536 + rstep + k0 + co, Bsb + i*4096 + w*1024);
        }
        __syncthreads();
        bf16x8 af[2][4], bfr[2][4];
        #pragma unroll
        for (int kk = 0; kk < 2; ++kk) {
            const int coff = (kk*64 + ((l >> 4) << 4)) ^ rsw;
            #pragma unroll
            for (int mi = 0; mi < 4; ++mi) {
                const int rowA = wr*64 + mi*16 + (l & 15);
                af[kk][mi]  = *(const bf16x8*)(Asb + rowA*128 + coff);
                const int rowB = wc*64 + mi*16 + (l & 15);
                bfr[kk][mi] = *(const bf16x8*)(Bsb + rowB*128 + coff);
            }
        }
        #pragma unroll
        for (int mi = 0; mi < 4; ++mi)
            #pragma unroll
            for (int nj = 0; nj < 4; ++nj) {
                acc[mi][nj] = __builtin_amdgcn_mfma_f32_16x16x32_bf16(
                                  af[0][mi], bfr[0][nj], acc[mi][nj], 0, 0, 0);
                acc[mi][nj] = __builtin_amdgcn_mfma_f32_16x16x32_bf16(
                                  af[1][mi], bfr[1][nj], acc[mi][nj], 0, 0, 0);
            }
        __syncthreads();
    }
}

// =======================================================================
// K0: q/v projection + FUSED q-normalize. xbf [16384][768], wqv [1536][768].
// bj<6 -> q cols: each wave's 64 cols = one head (h = 2bj+wc); row-norm via
// 16-lane shfl_xor reduce over nj-frags; writes qn bf16 [bh][n][64] direct.
// bj>=6 -> v cols, written TRANSPOSED as vbfT [bh][d][m] bf16.
// =======================================================================
__global__ __launch_bounds__(256)
void gemm_qkv_mfma(const u16* __restrict__ xbf, const u16* __restrict__ wqv,
                   u16* __restrict__ qnbf, u16* __restrict__ vbfT)
{
    __shared__ u16 As[128*64];
    __shared__ u16 Bs[128*64];
    const int m0 = blockIdx.x * 128;
    const int bj = blockIdx.y;
    const int tid = threadIdx.x;
    f32x4 acc[4][4];
    #pragma unroll
    for (int i = 0; i < 4; ++i)
        #pragma unroll
        for (int j = 0; j < 4; ++j) acc[i][j] = (f32x4){0.f,0.f,0.f,0.f};

    mfma_gemm_core((const char*)xbf + (size_t)m0*1536,
                   (const char*)wqv + (size_t)bj*128*1536,
                   As, Bs, tid, acc);

    const int l = tid & 63, w = tid >> 6;
    const int wr = w >> 1, wc = w & 1;
    const int rbase = m0 + wr*64 + ((l >> 4) << 2);
    if (bj < 6) {
        const int h = 2*bj + wc;                   // wave's 64 cols = head h
        #pragma unroll
        for (int mi = 0; mi < 4; ++mi)
            #pragma unroll
            for (int rr = 0; rr < 4; ++rr) {
                float s =      acc[mi][0][rr]*acc[mi][0][rr];
                s = fmaf(acc[mi][1][rr], acc[mi][1][rr], s);
                s = fmaf(acc[mi][2][rr], acc[mi][2][rr], s);
                s = fmaf(acc[mi][3][rr], acc[mi][3][rr], s);
                #pragma unroll
                for (int off = 1; off < 16; off <<= 1) s += __shfl_xor(s, off);
                const float inv = 1.0f / (sqrtf(s) + 1e-8f);
                const int m = rbase + mi*16 + rr;
                const int b_ = m >> 8, n_ = m & 255;
                u16* row = qnbf + ((((size_t)b_*12 + h) << 8) + n_)*64;
                #pragma unroll
                for (int nj = 0; nj < 4; ++nj)
                    row[nj*16 + (l & 15)] = f2bf(acc[mi][nj][rr] * inv);
            }
    } else {
        const int colb = (bj - 6)*128 + wc*64;
        #pragma unroll
        for (int mi = 0; mi < 4; ++mi)
            #pragma unroll
            for (int nj = 0; nj < 4; ++nj) {
                const int col = colb + nj*16 + (l & 15);
                const int h = col >> 6, d = col & 63;
                const int m = rbase + mi*16;        // rows m..m+3 (consecutive)
                const int b_ = m >> 8, n_ = m & 255;
                uint2 o = make_uint2(pack2bf(acc[mi][nj][0], acc[mi][nj][1]),
                                     pack2bf(acc[mi][nj][2], acc[mi][nj][3]));
                *(uint2*)&vbfT[(((size_t)b_*12 + h)*64 + d)*256 + n_] = o;
            }
    }
}

// =======================================================================
// K5: out = ctx @ w_proj^T + b_proj. ctxb [16384][768] bf16, wpb [768][768] bf16.
// =======================================================================
__global__ __launch_bounds__(256)
void gemm_proj_mfma(const u16* __restrict__ ctxb, const u16* __restrict__ wpb,
                    const float* __restrict__ bias, float* __restrict__ out)
{
    __shared__ u16 As[128*64];
    __shared__ u16 Bs[128*64];
    const int m0 = blockIdx.x * 128;
    const int n0 = blockIdx.y * 128;
    const int tid = threadIdx.x;
    f32x4 acc[4][4];
    #pragma unroll
    for (int i = 0; i < 4; ++i)
        #pragma unroll
        for (int j = 0; j < 4; ++j) acc[i][j] = (f32x4){0.f,0.f,0.f,0.f};

    mfma_gemm_core((const char*)ctxb + (size_t)m0*1536,
                   (const char*)wpb + (size_t)n0*1536,
                   As, Bs, tid, acc);

    const int l = tid & 63, w = tid >> 6;
    const int wr = w >> 1, wc = w & 1;
    const int rbase = m0 + wr*64 + ((l >> 4) << 2);
    #pragma unroll
    for (int mi = 0; mi < 4; ++mi)
        #pragma unroll
        for (int nj = 0; nj < 4; ++nj) {
            const int col = n0 + wc*64 + nj*16 + (l & 15);
            const float bv = bias[col];
            #pragma unroll
            for (int rr = 0; rr < 4; ++rr) {
                const int m = rbase + mi*16 + rr;
                out[(size_t)m*768 + col] = acc[mi][nj][rr] + bv;
            }
        }
}

// =======================================================================
// K2: K[n][m] = exp(10*cos(n,m) - 10) off-diag, 0 on diag. bf16 out.
// MFMA on qn bf16 tiles, XOR-swizzled LDS, fused exp epilogue.
// =======================================================================
__global__ __launch_bounds__(256)
void cost_kernel(const u16* __restrict__ qnbf, u16* __restrict__ Kmat)
{
    __shared__ u16 Qa[128*64];     // [row][64 k] bf16, slot s holds global slot s^(row&7)
    __shared__ u16 Qb[128*64];
    const int bh = blockIdx.y;
    const int tr = (blockIdx.x >> 1) * 128;
    const int tc = (blockIdx.x & 1) * 128;
    const char* qb = (const char*)(qnbf + (size_t)bh * 16384);
    const int tid = threadIdx.x;
    const int l = tid & 63, w = tid >> 6;
    const int wr = w >> 1, wc = w & 1;

    // ---- stage both tiles: 4 issues/wave/array; rows 8*(i*4+w)+(l>>3)
    {
        const int co = ((l & 7) ^ (l >> 3)) << 4;   // inverse-swizzled source slot
        const int rl = l >> 3;
        #pragma unroll
        for (int i = 0; i < 4; ++i) {
            const int ch = i*4 + w;                 // chunk 0..15
            gload_lds16(qb + (size_t)(tr + ch*8 + rl)*128 + co, (char*)Qa + ch*1024);
            gload_lds16(qb + (size_t)(tc + ch*8 + rl)*128 + co, (char*)Qb + ch*1024);
        }
    }
    __syncthreads();

    f32x4 acc[4][4];
    #pragma unroll
    for (int i = 0; i < 4; ++i)
        #pragma unroll
        for (int j = 0; j < 4; ++j) acc[i][j] = (f32x4){0.f,0.f,0.f,0.f};

    bf16x8 af[2][4], bfr[2][4];
    #pragma unroll
    for (int kk = 0; kk < 2; ++kk) {
        const int kb = kk*64 + ((l >> 4) << 4);
        #pragma unroll
        for (int f = 0; f < 4; ++f) {
            const int ra = wr*64 + f*16 + (l & 15);
            af[kk][f]  = *(const bf16x8*)((char*)Qa + ra*128 + (kb ^ ((ra & 7) << 4)));
            const int rb = wc*64 + f*16 + (l & 15);
            bfr[kk][f] = *(const bf16x8*)((char*)Qb + rb*128 + (kb ^ ((rb & 7) << 4)));
        }
    }
    #pragma unroll
    for (int mi = 0; mi < 4; ++mi)
        #pragma unroll
        for (int nj = 0; nj < 4; ++nj) {
            acc[mi][nj] = __builtin_amdgcn_mfma_f32_16x16x32_bf16(
                              af[0][mi], bfr[0][nj], acc[mi][nj], 0, 0, 0);
            acc[mi][nj] = __builtin_amdgcn_mfma_f32_16x16x32_bf16(
                              af[1][mi], bfr[1][nj], acc[mi][nj], 0, 0, 0);
        }

    // ---- epilogue: exp(10*s - 10), diag -> 0, bf16 store
    u16* Kb = Kmat + (size_t)bh * 65536;
    #pragma unroll
    for (int mi = 0; mi < 4; ++mi)
        #pragma unroll
        for (int nj = 0; nj < 4; ++nj) {
            const int gr0 = tr + wr*64 + mi*16 + ((l >> 4) << 2);
            const int gc  = tc + wc*64 + nj*16 + (l & 15);
            #pragma unroll
            for (int rr = 0; rr < 4; ++rr) {
                const int gr = gr0 + rr;
                const float s = acc[mi][nj][rr];
                const float km = (gr == gc) ? 0.f : __expf(fmaf(10.f, s, -10.f));
                Kb[(size_t)gr * 256 + gc] = f2bf(km);
            }
        }
}

// =======================================================================
// K3 (split A): Sinkhorn iterations + Tmax only. K in MFMA A-frags (wave w
// owns rows 32w..32w+31); 20 matvecs y=Kx on matrix cores (B = x broadcast,
// D column-redundant so every lane holds its 8 rows' y); owner-computes
// xn = (1/256)*rcp(y); ONE barrier/iter. Phase 2: Tmax = u*max(k*v),
// u factored out. Writes u, v (fp32) and tmax to global for the PV kernel.
// =======================================================================
__global__ __launch_bounds__(512, 2)
void sinkhorn_kernel(const u16* __restrict__ Kmat, float* __restrict__ ubuf,
                     float* __restrict__ vbuf, float* __restrict__ tmaxbuf)
{
    __shared__ __align__(16) float xv[256];
    __shared__ __align__(16) float usave[256];
    __shared__ __align__(16) u16   xbf[256];
    __shared__ float pmax[8];
    const int bh  = blockIdx.x;
    const int tid = threadIdx.x;
    const int l = tid & 63, w = tid >> 6;
    const int rowb = w * 32;
    const char* Kg = (const char*)(Kmat + (size_t)bh * 65536);

    // ---- K frags: lane l holds K[rowb + t*16 + (l&15)][ks*32 + (l>>4)*8 + j]
    bf16x8 kf[2][8];
    {
        const char* kb0 = Kg + (size_t)(rowb + (l & 15)) * 512 + ((l >> 4) << 4);
        #pragma unroll
        for (int t = 0; t < 2; ++t)
            #pragma unroll
            for (int ks = 0; ks < 8; ++ks)
                kf[t][ks] = *(const bf16x8*)(kb0 + t*8192 + ks*64);
    }
    if (tid < 256) xbf[tid] = 0x3f80;    // bf16(1.0)
    __syncthreads();

    // ---- Phase 1: 20 half-iterations, ONE barrier each
    for (int it = 0; it < 20; ++it) {
        f32x4 a0a = {0.f,0.f,0.f,0.f}, a0b = {0.f,0.f,0.f,0.f};
        f32x4 a1a = {0.f,0.f,0.f,0.f}, a1b = {0.f,0.f,0.f,0.f};
        #pragma unroll
        for (int ks = 0; ks < 4; ++ks) {
            const bf16x8 xf = *(const bf16x8*)((const char*)xbf + ks*64 + ((l >> 4) << 4));
            a0a = __builtin_amdgcn_mfma_f32_16x16x32_bf16(kf[0][ks], xf, a0a, 0, 0, 0);
            a1a = __builtin_amdgcn_mfma_f32_16x16x32_bf16(kf[1][ks], xf, a1a, 0, 0, 0);
        }
        #pragma unroll
        for (int ks = 4; ks < 8; ++ks) {
            const bf16x8 xf = *(const bf16x8*)((const char*)xbf + ks*64 + ((l >> 4) << 4));
            a0b = __builtin_amdgcn_mfma_f32_16x16x32_bf16(kf[0][ks], xf, a0b, 0, 0, 0);
            a1b = __builtin_amdgcn_mfma_f32_16x16x32_bf16(kf[1][ks], xf, a1b, 0, 0, 0);
        }
        float xn0[4], xn1[4];
        #pragma unroll
        for (int j = 0; j < 4; ++j) {
            xn0[j] = 0.00390625f * __builtin_amdgcn_rcpf(a0a[j] + a0b[j]);
            xn1[j] = 0.00390625f * __builtin_amdgcn_rcpf(a1a[j] + a1b[j]);
        }
        const u32 xp0 = cvtpk2bf(xn0[0], xn0[1]);
        const u32 xp1 = cvtpk2bf(xn0[2], xn0[3]);
        const u32 xp2 = cvtpk2bf(xn1[0], xn1[1]);
        const u32 xp3 = cvtpk2bf(xn1[2], xn1[3]);
        if ((l & 15) == 0) {
            const int r0 = rowb + ((l >> 4) << 2);
            *(uint2*)&xbf[r0]      = make_uint2(xp0, xp1);
            *(uint2*)&xbf[r0 + 16] = make_uint2(xp2, xp3);
            if (it == 18) {
                *(float4*)&usave[r0]      = make_float4(xn0[0], xn0[1], xn0[2], xn0[3]);
                *(float4*)&usave[r0 + 16] = make_float4(xn1[0], xn1[1], xn1[2], xn1[3]);
            }
            if (it == 19) {
                *(float4*)&xv[r0]      = make_float4(xn0[0], xn0[1], xn0[2], xn0[3]);
                *(float4*)&xv[r0 + 16] = make_float4(xn1[0], xn1[1], xn1[2], xn1[3]);
            }
        }
        __syncthreads();
    }

    // ---- Phase 2: Tmax = max u[n] K[n][m] v[m] = u[n] * max_m(K*v)
    {
        float mx0 = 0.f, mx1 = 0.f;
        #pragma unroll
        for (int ks = 0; ks < 8; ++ks) {
            const int mbase = ks*32 + ((l >> 4) << 3);
            const float4 va  = *(const float4*)&xv[mbase];
            const float4 vb4 = *(const float4*)&xv[mbase + 4];
            const float vv[8] = {va.x, va.y, va.z, va.w, vb4.x, vb4.y, vb4.z, vb4.w};
            #pragma unroll
            for (int j = 0; j < 8; ++j) {
                mx0 = fmaxf(mx0, bf2f((u16)kf[0][ks][j]) * vv[j]);
                mx1 = fmaxf(mx1, bf2f((u16)kf[1][ks][j]) * vv[j]);
            }
        }
        float mx = fmaxf(usave[rowb + (l & 15)] * mx0,
                         usave[rowb + 16 + (l & 15)] * mx1);
        #pragma unroll
        for (int off = 32; off > 0; off >>= 1) mx = fmaxf(mx, __shfl_xor(mx, off));
        if (l == 0) pmax[w] = mx;
    }
    __syncthreads();
    if (tid < 256) {
        ubuf[bh * 256 + tid] = usave[tid];
        vbuf[bh * 256 + tid] = xv[tid];
    }
    if (tid == 0) {
        float tm = pmax[0];
        #pragma unroll
        for (int i = 1; i < 8; ++i) tm = fmaxf(tm, pmax[i]);
        tmaxbuf[bh] = tm;
    }
}

// =======================================================================
// K4 (split B): P + PV. Reloads K frags (same layout as A), stages Vt (XOR-
// swizzled) + v into LDS; per t-half, per ks: P-frag built elementwise
// (exp, diag override, cvt_pk) and consumed immediately by 4 MFMAs
// (D[d][n] += Vt-frag x P-frag). psum lane-local via 2 shfl_xor. No serial
// section -> pure throughput.
// =======================================================================
__global__ __launch_bounds__(512, 2)
void pv_kernel(const u16* __restrict__ Kmat, const u16* __restrict__ vbfT,
               const float* __restrict__ ubuf, const float* __restrict__ vbuf,
               const float* __restrict__ tmaxbuf, u16* __restrict__ ctxc)
{
    __shared__ u16 Vt[64*256];       // 32 KB, slot s of row d holds global slot s^(d&7)
    __shared__ __align__(16) float xv[256];
    const int bh  = blockIdx.x;
    const int b_ = bh / 12, h_ = bh - b_*12;
    const int tid = threadIdx.x;
    const int l = tid & 63, w = tid >> 6;
    const int rowb = w * 32;
    const char* Kg = (const char*)(Kmat + (size_t)bh * 65536);

    // ---- stage Vt (32 KB): 4 issues x (512 thr x 16B); source pre-swizzled
    {
        const char* src = (const char*)(vbfT + (size_t)bh * 16384);
        char* dst = (char*)Vt;
        const int s = l & 31;
        #pragma unroll
        for (int i = 0; i < 4; ++i) {
            const int d = i*16 + w*2 + (l >> 5);
            gload_lds16(src + d*512 + ((s ^ (d & 7)) << 4), dst + i*8192 + w*1024);
        }
    }
    if (tid < 256) xv[tid] = vbuf[bh*256 + tid];

    // ---- K frags: lane l holds K[rowb + t*16 + (l&15)][ks*32 + (l>>4)*8 + j]
    bf16x8 kf[2][8];
    {
        const char* kb0 = Kg + (size_t)(rowb + (l & 15)) * 512 + ((l >> 4) << 4);
        #pragma unroll
        for (int t = 0; t < 2; ++t)
            #pragma unroll
            for (int ks = 0; ks < 8; ++ks)
                kf[t][ks] = *(const bf16x8*)(kb0 + t*8192 + ks*64);
    }
    const float itmax = 1.0f / tmaxbuf[bh];
    const float u0 = ubuf[bh*256 + rowb + (l & 15)];
    const float u1 = ubuf[bh*256 + rowb + 16 + (l & 15)];
    __syncthreads();                 // Vt + xv resident

    // ---- per t-half: P frag -> immediate PV MFMA
    u16* outp = ctxc + ((size_t)b_*256)*768 + h_*64;
    #pragma unroll
    for (int t = 0; t < 2; ++t) {
        const int rown = rowb + t*16 + (l & 15);
        const float an = (t == 0 ? u0 : u1) * itmax * 0.125f;
        float psum = 0.f;
        f32x4 acc0 = {0.f,0.f,0.f,0.f}, acc1 = {0.f,0.f,0.f,0.f};
        f32x4 acc2 = {0.f,0.f,0.f,0.f}, acc3 = {0.f,0.f,0.f,0.f};
        #pragma unroll
        for (int ks = 0; ks < 8; ++ks) {
            const int mbase = ks*32 + ((l >> 4) << 3);
            const float4 va  = *(const float4*)&xv[mbase];
            const float4 vb4 = *(const float4*)&xv[mbase + 4];
            const float vv[8] = {va.x, va.y, va.z, va.w, vb4.x, vb4.y, vb4.z, vb4.w};
            float p[8];
            #pragma unroll
            for (int j = 0; j < 8; ++j)
                p[j] = __expf(an * bf2f((u16)kf[t][ks][j]) * vv[j]);
            const int dj = rown - mbase;
            if (dj >= 0 && dj < 8) p[dj] = 1.13314845f;     // exp(0.125)
            psum += ((p[0]+p[1]) + (p[2]+p[3])) + ((p[4]+p[5]) + (p[6]+p[7]));
            uint4 pwv = make_uint4(cvtpk2bf(p[0], p[1]), cvtpk2bf(p[2], p[3]),
                                   cvtpk2bf(p[4], p[5]), cvtpk2bf(p[6], p[7]));
            const bf16x8 pf = *(const bf16x8*)&pwv;
            const int bc = ks*64 + ((l >> 4) << 4);
            {
                const int d = (l & 15);
                const bf16x8 vf = *(const bf16x8*)((char*)Vt + d*512 + (bc ^ ((d & 7) << 4)));
                acc0 = __builtin_amdgcn_mfma_f32_16x16x32_bf16(vf, pf, acc0, 0, 0, 0);
            }
            {
                const int d = 16 + (l & 15);
                const bf16x8 vf = *(const bf16x8*)((char*)Vt + d*512 + (bc ^ ((d & 7) << 4)));
                acc1 = __builtin_amdgcn_mfma_f32_16x16x32_bf16(vf, pf, acc1, 0, 0, 0);
            }
            {
                const int d = 32 + (l & 15);
                const bf16x8 vf = *(const bf16x8*)((char*)Vt + d*512 + (bc ^ ((d & 7) << 4)));
                acc2 = __builtin_amdgcn_mfma_f32_16x16x32_bf16(vf, pf, acc2, 0, 0, 0);
            }
            {
                const int d = 48 + (l & 15);
                const bf16x8 vf = *(const bf16x8*)((char*)Vt + d*512 + (bc ^ ((d & 7) << 4)));
                acc3 = __builtin_amdgcn_mfma_f32_16x16x32_bf16(vf, pf, acc3, 0, 0, 0);
            }
        }
        psum += __shfl_xor(psum, 16);
        psum += __shfl_xor(psum, 32);                  // 4 lanes/row summed
        const float is = 1.0f / psum;
        const int d0 = (l >> 4) << 2;
        uint2 o0 = make_uint2(cvtpk2bf(acc0[0]*is, acc0[1]*is), cvtpk2bf(acc0[2]*is, acc0[3]*is));
        uint2 o1 = make_uint2(cvtpk2bf(acc1[0]*is, acc1[1]*is), cvtpk2bf(acc1[2]*is, acc1[3]*is));
        uint2 o2 = make_uint2(cvtpk2bf(acc2[0]*is, acc2[1]*is), cvtpk2bf(acc2[2]*is, acc2[3]*is));
        uint2 o3 = make_uint2(cvtpk2bf(acc3[0]*is, acc3[1]*is), cvtpk2bf(acc3[2]*is, acc3[3]*is));
        u16* orow = outp + (size_t)rown*768;
        *(uint2*)&orow[d0]      = o0;
        *(uint2*)&orow[16 + d0] = o1;
        *(uint2*)&orow[32 + d0] = o2;
        *(uint2*)&orow[48 + d0] = o3;
    }
}

// =======================================================================
extern "C" void kernel_launch(void* const* d_in, const int* in_sizes, int n_in,
                              void* d_out, int out_size, void* d_ws, size_t ws_size,
                              hipStream_t stream)
{
    (void)in_sizes; (void)n_in; (void)out_size; (void)ws_size;
    const float* x      = (const float*)d_in[0];
    const float* w_qkv  = (const float*)d_in[1];
    const float* w_proj = (const float*)d_in[2];
    const float* b_proj = (const float*)d_in[3];
    float* out = (float*)d_out;

    char* w = (char*)d_ws;
    // workspace layout (bytes):
    u16*   xbf  = (u16*)  (w);                     //  25,165,824  x bf16 [16384][768]
    u16*   wqv  = (u16*)  (w + 25165824);          //   2,359,296  w q+v rows bf16 [1536][768]
    u16*   wpb  = (u16*)  (w + 27525120);          //   1,179,648  w_proj bf16 [768][768]
    u16*   qnbf = (u16*)  (w + 28704768);          //  25,165,824  qn bf16 [768][256][64]
    u16*   vbfT = (u16*)  (w + 79036416);          //  25,165,824  v^T bf16 [768][64][256]
    u16*   ctxc = (u16*)  (w + 104202240);         //  25,165,824  ctx bf16 [64][256][768]
    float* ub   = (float*)(w + 129368064);         //     786,432  u [768][256]
    float* vb   = (float*)(w + 130154496);         //     786,432  v [768][256]
    float* tmx  = (float*)(w + 130940928);         //       3,072  tmax [768]
    u16*   Km   = (u16*)  (w + 130944000);         // 100,663,296  K bf16 [768][256][256]
    // total ~231.6 MB

    conv_bf16      <<<dim3(6144),    256, 0, stream>>>(x, xbf, 1572864);
    conv_wqv       <<<dim3(576),     256, 0, stream>>>(w_qkv, wqv);
    conv_bf16      <<<dim3(288),     256, 0, stream>>>(w_proj, wpb, 73728);
    gemm_qkv_mfma  <<<dim3(128, 12), 256, 0, stream>>>(xbf, wqv, qnbf, vbfT);
    cost_kernel    <<<dim3(4, 768),  256, 0, stream>>>(qnbf, Km);
    sinkhorn_kernel<<<dim3(768),     512, 0, stream>>>(Km, ub, vb, tmx);
    pv_kernel      <<<dim3(768),     512, 0, stream>>>(Km, vbfT, ub, vb, tmx, ctxc);
    gemm_proj_mfma <<<dim3(128, 6),  256, 0, stream>>>(ctxc, wpb, b_proj, out);
}